// Round 4
// baseline (612.863 us; speedup 1.0000x reference)
//
#include <hip/hip_runtime.h>

#define DIMC 128
#define NHEADS 4
#define HD 32
#define HID 256
#define BB 4
#define HH_ 128
#define WW_ 128
#define HW 16384
#define RS 16
#define STEP 14
#define NR 9
#define NREGB 81
#define NREG 324
#define TT 256

typedef unsigned short bfu;  // bf16 bits
typedef __attribute__((ext_vector_type(8))) short bf16x8;
typedef __attribute__((ext_vector_type(4))) float f32x4;

__device__ __forceinline__ float bf2f(bfu u) {
  return __uint_as_float(((unsigned int)u) << 16);
}
__device__ __forceinline__ bfu f2bf(float f) {
  unsigned int i = __float_as_uint(f);
  unsigned int r = i + 0x7fffu + ((i >> 16) & 1u);
  return (bfu)(r >> 16);
}
__device__ __forceinline__ float gelu_exact(float x) {
  return 0.5f * x * (1.0f + erff(x * 0.70710678118654752f));
}
__device__ __forceinline__ void fma4x4(const float4 a, const float4 b, float acc[4][4]) {
  acc[0][0] = fmaf(b.x, a.x, acc[0][0]);
  acc[0][1] = fmaf(b.x, a.y, acc[0][1]);
  acc[0][2] = fmaf(b.x, a.z, acc[0][2]);
  acc[0][3] = fmaf(b.x, a.w, acc[0][3]);
  acc[1][0] = fmaf(b.y, a.x, acc[1][0]);
  acc[1][1] = fmaf(b.y, a.y, acc[1][1]);
  acc[1][2] = fmaf(b.y, a.z, acc[1][2]);
  acc[1][3] = fmaf(b.y, a.w, acc[1][3]);
  acc[2][0] = fmaf(b.z, a.x, acc[2][0]);
  acc[2][1] = fmaf(b.z, a.y, acc[2][1]);
  acc[2][2] = fmaf(b.z, a.z, acc[2][2]);
  acc[2][3] = fmaf(b.z, a.w, acc[2][3]);
  acc[3][0] = fmaf(b.w, a.x, acc[3][0]);
  acc[3][1] = fmaf(b.w, a.y, acc[3][1]);
  acc[3][2] = fmaf(b.w, a.z, acc[3][2]);
  acc[3][3] = fmaf(b.w, a.w, acc[3][3]);
}

// KPREP: block 24 zeros bnacc; blocks 0..23 build wqkvT bf16 blocked
// [kg(16)][n(384)][8k]  (B-fragment-native order)
__global__ __launch_bounds__(256) void kprep(
    const float* __restrict__ wqkv, bfu* __restrict__ wqkvT,
    float* __restrict__ bnacc) {
  int bid = blockIdx.x;
  if (bid == 24) {
    int t = threadIdx.x;
    bnacc[t] = 0.f;
    bnacc[256 + t] = 0.f;
    return;
  }
  int task = bid * 256 + threadIdx.x;  // kg*384 + n
  int kg = task / 384, n = task % 384;
  bfu tmp[8];
  #pragma unroll
  for (int j = 0; j < 8; ++j) tmp[j] = f2bf(wqkv[(kg * 8 + j) * 384 + n]);
  *(uint4*)&wqkvT[(size_t)kg * 3072 + n * 8] = *(const uint4*)tmp;
}

// K1: gather -> tok fp32 [reg][c][t]; aln bf16 blocked [reg][g=c/8][t][8c]
// (A-fragment-native order, fully coalesced 16B stores)
__global__ __launch_bounds__(256) void k1_gather(
    const float* __restrict__ x, const float* __restrict__ g,
    const float* __restrict__ bia, float* __restrict__ tok,
    bfu* __restrict__ aln) {
  int reg = blockIdx.x;
  int b = reg / NREGB, ij = reg % NREGB;
  int i = ij / NR, j = ij % NR;
  int t = threadIdx.x;
  int r = t >> 4, s = t & 15;
  int hh = i * STEP + r, ww = j * STEP + s;
  const float* xp = x + (size_t)b * DIMC * HW + (size_t)hh * WW_ + ww;
  float* tp = tok + (size_t)reg * DIMC * TT + t;
  float sum = 0.f, sq = 0.f;
  #pragma unroll 4
  for (int c = 0; c < DIMC; ++c) {
    float v = xp[(size_t)c * HW];
    tp[c * TT] = v;
    sum += v;
    sq = fmaf(v, v, sq);
  }
  float mu = sum * (1.0f / DIMC);
  float var = sq * (1.0f / DIMC) - mu * mu;
  float rstd = rsqrtf(var + 1e-5f);
  bfu* ap = aln + (size_t)reg * 32768 + t * 8;
  #pragma unroll
  for (int gidx = 0; gidx < 16; ++gidx) {
    bfu tmp[8];
    #pragma unroll
    for (int jj = 0; jj < 8; ++jj) {
      int c = gidx * 8 + jj;
      float vv = xp[(size_t)c * HW];  // L2-hot re-read
      tmp[jj] = f2bf((vv - mu) * rstd * g[c] + bia[c]);
    }
    *(uint4*)&ap[(size_t)gidx * 2048] = *(const uint4*)tmp;
  }
}

// K2: LDS-free register MFMA GEMM. Block=(reg, 64-token group), 4 waves
// each 64tok x 96n. A/B frags loaded directly from blocked global layouts.
__global__ __launch_bounds__(256) void k2_qkv(
    const bfu* __restrict__ aln, const bfu* __restrict__ wqkvT,
    bfu* __restrict__ qkvt) {
  int reg = blockIdx.x;
  int mt = blockIdx.y;
  int tid = threadIdx.x;
  int wave = tid >> 6, lane = tid & 63;
  int quad = lane >> 4, n16 = lane & 15;
  const bfu* ab = aln + (size_t)reg * 32768 + (mt * 64 + n16) * 8;
  const bfu* bb = wqkvT + (wave * 96 + n16) * 8;
  f32x4 acc[4][6];
  #pragma unroll
  for (int m = 0; m < 4; ++m)
    #pragma unroll
    for (int nt = 0; nt < 6; ++nt) acc[m][nt] = (f32x4){0.f, 0.f, 0.f, 0.f};
  #pragma unroll
  for (int ph = 0; ph < 4; ++ph) {
    int gg = ph * 4 + quad;
    bf16x8 af[4];
    #pragma unroll
    for (int m = 0; m < 4; ++m)
      af[m] = *(const bf16x8*)&ab[(size_t)gg * 2048 + m * 128];
    bf16x8 bfr[6];
    #pragma unroll
    for (int nt = 0; nt < 6; ++nt)
      bfr[nt] = *(const bf16x8*)&bb[(size_t)gg * 3072 + nt * 128];
    #pragma unroll
    for (int m = 0; m < 4; ++m)
      #pragma unroll
      for (int nt = 0; nt < 6; ++nt)
        acc[m][nt] =
            __builtin_amdgcn_mfma_f32_16x16x32_bf16(af[m], bfr[nt], acc[m][nt], 0, 0, 0);
  }
  bfu* outp =
      qkvt + ((size_t)reg * 256 + mt * 64 + quad * 4) * 384 + wave * 96 + n16;
  #pragma unroll
  for (int m = 0; m < 4; ++m)
    #pragma unroll
    for (int nt = 0; nt < 6; ++nt)
      #pragma unroll
      for (int r = 0; r < 4; ++r)
        outp[(m * 16 + r) * 384 + nt * 16] = f2bf(acc[m][nt][r]);
}

// K3: MFMA attention (unchanged)
__global__ __launch_bounds__(256, 2) void k3_attn(
    const bfu* __restrict__ qkvt, bfu* __restrict__ o) {
  int reg = blockIdx.x;
  int h = blockIdx.y;
  __shared__ __align__(16) bfu sVt[32 * 264];
  __shared__ __align__(16) bfu sP[4][16 * 264];
  int tid = threadIdx.x;
  int wave = tid >> 6, lane = tid & 63;
  int quad = lane >> 4, n16 = lane & 15;
  const bfu* qb = qkvt + (size_t)reg * 256 * 384;
  {
    const bfu* vrow = qb + tid * 384 + 256 + h * 32;
    #pragma unroll
    for (int dg = 0; dg < 8; ++dg) {
      ushort4 v4 = *(const ushort4*)(vrow + dg * 4);
      sVt[(dg * 4 + 0) * 264 + tid] = v4.x;
      sVt[(dg * 4 + 1) * 264 + tid] = v4.y;
      sVt[(dg * 4 + 2) * 264 + tid] = v4.z;
      sVt[(dg * 4 + 3) * 264 + tid] = v4.w;
    }
  }
  __syncthreads();
  bf16x8 vf[2][8];
  #pragma unroll
  for (int nt = 0; nt < 2; ++nt)
    #pragma unroll
    for (int kt = 0; kt < 8; ++kt)
      vf[nt][kt] = *(const bf16x8*)&sVt[(nt * 16 + n16) * 264 + kt * 32 + quad * 8];
  const bfu* kptr = qb + n16 * 384 + 128 + h * 32 + quad * 8;
  const f32x4 zero = {0.f, 0.f, 0.f, 0.f};
  const float scale = 0.17677669529663687f;
  bfu* pw = sP[wave];
  for (int mi = 0; mi < 4; ++mi) {
    int mt = wave * 4 + mi;
    bf16x8 qf = *(const bf16x8*)(qb + (mt * 16 + n16) * 384 + h * 32 + quad * 8);
    f32x4 st[16];
    #pragma unroll
    for (int T = 0; T < 16; ++T) {
      bf16x8 kf = *(const bf16x8*)(kptr + T * 16 * 384);
      st[T] = __builtin_amdgcn_mfma_f32_16x16x32_bf16(qf, kf, zero, 0, 0, 0);
    }
    float inv[4];
    #pragma unroll
    for (int r = 0; r < 4; ++r) {
      float m = st[0][r];
      #pragma unroll
      for (int T = 1; T < 16; ++T) m = fmaxf(m, st[T][r]);
      #pragma unroll
      for (int mk = 1; mk < 16; mk <<= 1) m = fmaxf(m, __shfl_xor(m, mk, 64));
      float l = 0.f;
      #pragma unroll
      for (int T = 0; T < 16; ++T) {
        float p = __expf((st[T][r] - m) * scale);
        st[T][r] = p;
        l += p;
      }
      #pragma unroll
      for (int mk = 1; mk < 16; mk <<= 1) l += __shfl_xor(l, mk, 64);
      inv[r] = 1.0f / l;
    }
    #pragma unroll
    for (int T = 0; T < 16; ++T) {
      #pragma unroll
      for (int r = 0; r < 4; ++r)
        pw[(quad * 4 + r) * 264 + T * 16 + n16] = f2bf(st[T][r]);
    }
    __builtin_amdgcn_wave_barrier();
    f32x4 oa0 = zero, oa1 = zero;
    #pragma unroll
    for (int kt = 0; kt < 8; ++kt) {
      bf16x8 pf = *(const bf16x8*)&pw[n16 * 264 + kt * 32 + quad * 8];
      oa0 = __builtin_amdgcn_mfma_f32_16x16x32_bf16(pf, vf[0][kt], oa0, 0, 0, 0);
      oa1 = __builtin_amdgcn_mfma_f32_16x16x32_bf16(pf, vf[1][kt], oa1, 0, 0, 0);
    }
    __builtin_amdgcn_wave_barrier();
    bfu* ob = o + ((size_t)reg * 256 + mt * 16 + quad * 4) * 128 + h * 32 + n16;
    #pragma unroll
    for (int r = 0; r < 4; ++r) {
      ob[r * 128] = f2bf(oa0[r] * inv[r]);
      ob[r * 128 + 16] = f2bf(oa1[r] * inv[r]);
    }
  }
}

// K4: tok[c][t] += o @ w_out + b_out (o token-major, LDS transpose)
__global__ __launch_bounds__(256) void k4_outproj(
    const bfu* __restrict__ o, const float* __restrict__ wout,
    const float* __restrict__ bout, float* __restrict__ tok) {
  int reg = blockIdx.x;
  int ct = blockIdx.y >> 2, tt = blockIdx.y & 3;
  __shared__ float As[128 * 64];
  __shared__ float Bs[64 * 68];
  int tid = threadIdx.x;
  for (int idx = tid; idx < 8192; idx += 256) {
    int k = idx >> 6, l = idx & 63;
    As[idx] = wout[k * 128 + ct * 64 + l];
  }
  int ti = tid & 15, tj = tid >> 4;
  float acc[4][4] = {};
  const bfu* ob = o + (size_t)reg * 256 * 128;
  for (int ph = 0; ph < 2; ++ph) {
    __syncthreads();
    for (int idx = tid; idx < 4096; idx += 256) {
      int l = idx >> 6, k = idx & 63;
      Bs[k * 68 + l] = bf2f(ob[(tt * 64 + l) * 128 + ph * 64 + k]);
    }
    __syncthreads();
    #pragma unroll 8
    for (int k = 0; k < 64; ++k) {
      float4 a = *(const float4*)&Bs[k * 68 + ti * 4];
      float4 bb = *(const float4*)&As[(ph * 64 + k) * 64 + tj * 4];
      fma4x4(a, bb, acc);
    }
  }
  float* tokr = tok + (size_t)reg * DIMC * TT;
  #pragma unroll
  for (int jj = 0; jj < 4; ++jj) {
    int c = ct * 64 + tj * 4 + jj;
    float bo = bout[c];
    float4 res = *(const float4*)&tokr[c * TT + tt * 64 + ti * 4];
    res.x += acc[jj][0] + bo;
    res.y += acc[jj][1] + bo;
    res.z += acc[jj][2] + bo;
    res.w += acc[jj][3] + bo;
    *(float4*)&tokr[c * TT + tt * 64 + ti * 4] = res;
  }
}

// K5: overlap-average merge -> xf NCHW, fused LN2 per-pixel stats
__global__ __launch_bounds__(128) void k5_merge(
    const float* __restrict__ tok, float* __restrict__ xf,
    float* __restrict__ mu2, float* __restrict__ rstd2) {
  int hh = blockIdx.x, b = blockIdx.y;
  int w = threadIdx.x;
  int ilo = (hh >= 2) ? (hh - 2) / 14 : 0;
  int ihi = hh / 14;
  if (ihi > 8) ihi = 8;
  int jlo = (w >= 2) ? (w - 2) / 14 : 0;
  int jhi = w / 14;
  if (jhi > 8) jhi = 8;
  float rcnt = 1.0f / (float)((ihi - ilo + 1) * (jhi - jlo + 1));
  size_t offs[4];
  int nij = 0;
  for (int i = ilo; i <= ihi; ++i)
    for (int j = jlo; j <= jhi; ++j) {
      int reg = b * NREGB + i * NR + j;
      int r = hh - i * STEP, s = w - j * STEP;
      offs[nij++] = (size_t)reg * DIMC * TT + r * 16 + s;
    }
  float* xp = xf + ((size_t)b * DIMC << 14) + hh * WW_ + w;
  float sum = 0.f, sq = 0.f;
  for (int c = 0; c < DIMC; ++c) {
    float s = 0.f;
    for (int k = 0; k < nij; ++k) s += tok[offs[k] + c * TT];
    float m = s * rcnt;
    xp[(size_t)c << 14] = m;
    sum += m;
    sq = fmaf(m, m, sq);
  }
  float mu = sum * (1.0f / DIMC);
  float var = sq * (1.0f / DIMC) - mu * mu;
  int pg = (b << 14) + hh * WW_ + w;
  mu2[pg] = mu;
  rstd2[pg] = rsqrtf(var + 1e-5f);
}

// K6: ym = LN2(xf) @ w_p0 + b_p0 -> bf16 [b][f][p]
__global__ __launch_bounds__(256) void k6_p0(
    const float* __restrict__ xf, const float* __restrict__ mu2,
    const float* __restrict__ rstd2, const float* __restrict__ g,
    const float* __restrict__ bia, const float* __restrict__ wp0,
    const float* __restrict__ bp0, bfu* __restrict__ ym) {
  int pt = blockIdx.x, ft = blockIdx.y, b = blockIdx.z;
  __shared__ float As[128 * 64];
  __shared__ float Bs[128 * 64];
  int tid = threadIdx.x;
  for (int idx = tid; idx < 8192; idx += 256) {
    int c = idx >> 6, l = idx & 63;
    int p = pt * 64 + l;
    float v = xf[((size_t)(b * DIMC + c) << 14) + p];
    As[idx] = (v - mu2[(b << 14) + p]) * rstd2[(b << 14) + p] * g[c] + bia[c];
    Bs[idx] = wp0[c * HID + ft * 64 + l];
  }
  __syncthreads();
  int ti = tid & 15, tj = tid >> 4;
  float acc[4][4] = {};
  #pragma unroll 8
  for (int k = 0; k < 128; ++k) {
    float4 a = *(const float4*)&As[k * 64 + ti * 4];
    float4 bb = *(const float4*)&Bs[k * 64 + tj * 4];
    fma4x4(a, bb, acc);
  }
  #pragma unroll
  for (int jj = 0; jj < 4; ++jj) {
    int f = ft * 64 + tj * 4 + jj;
    float bo = bp0[f];
    ushort4 pk;
    pk.x = f2bf(acc[jj][0] + bo);
    pk.y = f2bf(acc[jj][1] + bo);
    pk.z = f2bf(acc[jj][2] + bo);
    pk.w = f2bf(acc[jj][3] + bo);
    *(ushort4*)&ym[((size_t)(b * HID + f) << 14) + pt * 64 + ti * 4] = pk;
  }
}

// K7: 5x5 depthwise conv, whole plane in LDS, fused BN partials
__global__ __launch_bounds__(256) void k7_conv(
    const bfu* __restrict__ ym, const float* __restrict__ dwk,
    bfu* __restrict__ ym2, float* __restrict__ bnacc) {
  int bf = blockIdx.x;
  int f = bf & (HID - 1);
  __shared__ bfu sp[128 * 134];
  const bfu* in = ym + ((size_t)bf << 14);
  int tid = threadIdx.x;
  for (int idx = tid; idx < 2048; idx += 256) {
    int r = idx >> 4, c8 = (idx & 15) << 3;
    ushort4 a = *(const ushort4*)&in[(r << 7) + c8];
    ushort4 b = *(const ushort4*)&in[(r << 7) + c8 + 4];
    bfu* d = &sp[r * 134 + c8];
    d[0] = a.x; d[1] = a.y; d[2] = a.z; d[3] = a.w;
    d[4] = b.x; d[5] = b.y; d[6] = b.z; d[7] = b.w;
  }
  float wk[25];
  #pragma unroll
  for (int i = 0; i < 25; ++i) wk[i] = dwk[f * 25 + i];
  __syncthreads();
  int row = tid >> 1, half = (tid & 1) << 6;
  float acc[64];
  #pragma unroll
  for (int i = 0; i < 64; ++i) acc[i] = 0.f;
  #pragma unroll
  for (int ky = 0; ky < 5; ++ky) {
    int y = row + ky - 2;
    if (y < 0 || y >= 128) continue;
    const bfu* rp = &sp[y * 134];
    float win[68];
    #pragma unroll
    for (int c = 0; c < 68; ++c) {
      int cc = half + c - 2;
      win[c] = (cc >= 0 && cc < 128) ? bf2f(rp[cc]) : 0.f;
    }
    #pragma unroll
    for (int kx = 0; kx < 5; ++kx) {
      float wv = wk[ky * 5 + kx];
      #pragma unroll
      for (int i = 0; i < 64; ++i) acc[i] = fmaf(win[i + kx], wv, acc[i]);
    }
  }
  float s = 0.f, sq = 0.f;
  #pragma unroll
  for (int i = 0; i < 64; ++i) {
    s += acc[i];
    sq = fmaf(acc[i], acc[i], sq);
  }
  bfu* op = ym2 + ((size_t)bf << 14) + (row << 7) + half;
  #pragma unroll
  for (int g8 = 0; g8 < 8; ++g8) {
    bfu tmp[8];
    #pragma unroll
    for (int i = 0; i < 8; ++i) tmp[i] = f2bf(acc[g8 * 8 + i]);
    *(uint4*)&op[g8 * 8] = *(const uint4*)tmp;
  }
  __syncthreads();
  float* red = (float*)sp;
  red[tid] = s;
  red[256 + tid] = sq;
  __syncthreads();
  for (int o = 128; o > 0; o >>= 1) {
    if (tid < o) {
      red[tid] += red[tid + o];
      red[256 + tid] += red[256 + tid + o];
    }
    __syncthreads();
  }
  if (tid == 0) {
    atomicAdd(&bnacc[f], red[0]);
    atomicAdd(&bnacc[HID + f], red[256]);
  }
}

// K8: finalize BN stats
__global__ __launch_bounds__(256) void k8_fin(
    const float* __restrict__ bnacc, float* __restrict__ bnm,
    float* __restrict__ bnr) {
  int f = threadIdx.x;
  float mu = bnacc[f] * (1.0f / 65536.f);
  float var = bnacc[HID + f] * (1.0f / 65536.f) - mu * mu;
  bnm[f] = mu;
  bnr[f] = rsqrtf(var + 1e-5f);
}

// K9: g2 = gelu(gelu(bn(ym2)))
__global__ __launch_bounds__(256) void k9_act(
    const bfu* __restrict__ ym2, const float* __restrict__ bnm,
    const float* __restrict__ bnr, const float* __restrict__ g,
    const float* __restrict__ bia, bfu* __restrict__ g2) {
  int base = (blockIdx.x * 256 + threadIdx.x) * 4;
  int f = (base >> 14) & (HID - 1);
  float mean = bnm[f];
  float sc = bnr[f] * g[f];
  float bb = bia[f];
  ushort4 rv = *(const ushort4*)&ym2[base];
  float v0 = (bf2f(rv.x) - mean) * sc + bb;
  float v1 = (bf2f(rv.y) - mean) * sc + bb;
  float v2 = (bf2f(rv.z) - mean) * sc + bb;
  float v3 = (bf2f(rv.w) - mean) * sc + bb;
  v0 = gelu_exact(gelu_exact(v0));
  v1 = gelu_exact(gelu_exact(v1));
  v2 = gelu_exact(gelu_exact(v2));
  v3 = gelu_exact(gelu_exact(v3));
  ushort4 pk;
  pk.x = f2bf(v0);
  pk.y = f2bf(v1);
  pk.z = f2bf(v2);
  pk.w = f2bf(v3);
  *(ushort4*)&g2[base] = pk;
}

// K10: out = g2 @ w_p2 + b_p2 + xf
__global__ __launch_bounds__(256) void k10_p2(
    const bfu* __restrict__ g2, const float* __restrict__ wp2,
    const float* __restrict__ bp2, const float* __restrict__ xf,
    float* __restrict__ outp) {
  int pt = blockIdx.x, ct = blockIdx.y, b = blockIdx.z;
  __shared__ float As[128 * 64];
  __shared__ float Bs[128 * 64];
  int tid = threadIdx.x;
  int ti = tid & 15, tj = tid >> 4;
  float acc[4][4] = {};
  for (int kt = 0; kt < 2; ++kt) {
    for (int idx = tid; idx < 8192; idx += 256) {
      int k = idx >> 6, l = idx & 63;
      int f = kt * 128 + k;
      As[idx] = bf2f(g2[((size_t)(b * HID + f) << 14) + pt * 64 + l]);
      Bs[idx] = wp2[f * DIMC + ct * 64 + l];
    }
    __syncthreads();
    #pragma unroll 8
    for (int k = 0; k < 128; ++k) {
      float4 a = *(const float4*)&As[k * 64 + ti * 4];
      float4 bb = *(const float4*)&Bs[k * 64 + tj * 4];
      fma4x4(a, bb, acc);
    }
    __syncthreads();
  }
  #pragma unroll
  for (int jj = 0; jj < 4; ++jj) {
    int c = ct * 64 + tj * 4 + jj;
    float bo = bp2[c];
    size_t off = ((size_t)(b * DIMC + c) << 14) + pt * 64 + ti * 4;
    float4 res = *(const float4*)&xf[off];
    res.x += acc[jj][0] + bo;
    res.y += acc[jj][1] + bo;
    res.z += acc[jj][2] + bo;
    res.w += acc[jj][3] + bo;
    *(float4*)&outp[off] = res;
  }
}

extern "C" void kernel_launch(void* const* d_in, const int* in_sizes, int n_in,
                              void* d_out, int out_size, void* d_ws,
                              size_t ws_size, hipStream_t stream) {
  const float* x = (const float*)d_in[0];
  const float* ln1_g = (const float*)d_in[1];
  const float* ln1_b = (const float*)d_in[2];
  const float* w_qkv = (const float*)d_in[3];
  const float* w_out = (const float*)d_in[4];
  const float* b_out = (const float*)d_in[5];
  const float* ln2_g = (const float*)d_in[6];
  const float* ln2_b = (const float*)d_in[7];
  const float* w_p0 = (const float*)d_in[8];
  const float* b_p0 = (const float*)d_in[9];
  const float* dw_k = (const float*)d_in[10];
  const float* bn_g = (const float*)d_in[11];
  const float* bn_b = (const float*)d_in[12];
  const float* w_p2 = (const float*)d_in[13];
  const float* b_p2 = (const float*)d_in[14];
  float* outp = (float*)d_out;

  char* ws = (char*)d_ws;
  size_t off = 0;
  auto alloc = [&](size_t bytes) {
    void* p = ws + off;
    off += (bytes + 1023) & ~(size_t)1023;
    return p;
  };
  float* tok = (float*)alloc((size_t)NREG * DIMC * TT * 4);
  bfu* qkvt = (bfu*)alloc((size_t)NREG * 384 * TT * 2);
  float* xf = (float*)alloc((size_t)BB * DIMC * HW * 4);
  float* mu2 = (float*)alloc((size_t)BB * HW * 4);
  float* rstd2 = (float*)alloc((size_t)BB * HW * 4);
  bfu* ym = (bfu*)alloc((size_t)BB * HID * HW * 2);
  bfu* ym2 = (bfu*)alloc((size_t)BB * HID * HW * 2);
  float* bnacc = (float*)alloc(2 * HID * 4);
  float* bnm = (float*)alloc(HID * 4);
  float* bnr = (float*)alloc(HID * 4);
  bfu* wqkvT = (bfu*)alloc(16 * 3072 * 2);
  // overlays (lifetimes disjoint)
  bfu* o = ym;     // used k3->k4; ym written first in k6
  bfu* aln = ym2;  // used k1->k2 (21.2 MB); ym2 written first in k7

  kprep<<<25, 256, 0, stream>>>(w_qkv, wqkvT, bnacc);
  k1_gather<<<NREG, 256, 0, stream>>>(x, ln1_g, ln1_b, tok, aln);
  k2_qkv<<<dim3(NREG, 4), 256, 0, stream>>>(aln, wqkvT, qkvt);
  k3_attn<<<dim3(NREG, NHEADS), 256, 0, stream>>>(qkvt, o);
  k4_outproj<<<dim3(NREG, 8), 256, 0, stream>>>(o, w_out, b_out, tok);
  k5_merge<<<dim3(HH_, BB), 128, 0, stream>>>(tok, xf, mu2, rstd2);
  k6_p0<<<dim3(256, 4, BB), 256, 0, stream>>>(xf, mu2, rstd2, ln2_g, ln2_b,
                                              w_p0, b_p0, ym);
  k7_conv<<<BB * HID, 256, 0, stream>>>(ym, dw_k, ym2, bnacc);
  k8_fin<<<1, 256, 0, stream>>>(bnacc, bnm, bnr);
  k9_act<<<16384, 256, 0, stream>>>(ym2, bnm, bnr, bn_g, bn_b, ym);
  k10_p2<<<dim3(256, 2, BB), 256, 0, stream>>>(ym, w_p2, b_p2, xf, outp);
}

// Round 5
// 529.002 us; speedup vs baseline: 1.1585x; 1.1585x over previous
//
#include <hip/hip_runtime.h>

#define DIMC 128
#define NHEADS 4
#define HD 32
#define HID 256
#define BB 4
#define HH_ 128
#define WW_ 128
#define HW 16384
#define RS 16
#define STEP 14
#define NR 9
#define NREGB 81
#define NREG 324
#define TT 256

typedef unsigned short bfu;  // bf16 bits
typedef __attribute__((ext_vector_type(8))) short bf16x8;
typedef __attribute__((ext_vector_type(4))) float f32x4;

__device__ __forceinline__ float bf2f(bfu u) {
  return __uint_as_float(((unsigned int)u) << 16);
}
__device__ __forceinline__ bfu f2bf(float f) {
  unsigned int i = __float_as_uint(f);
  unsigned int r = i + 0x7fffu + ((i >> 16) & 1u);
  return (bfu)(r >> 16);
}
__device__ __forceinline__ float gelu_exact(float x) {
  return 0.5f * x * (1.0f + erff(x * 0.70710678118654752f));
}
__device__ __forceinline__ void fma4x4(const float4 a, const float4 b, float acc[4][4]) {
  acc[0][0] = fmaf(b.x, a.x, acc[0][0]);
  acc[0][1] = fmaf(b.x, a.y, acc[0][1]);
  acc[0][2] = fmaf(b.x, a.z, acc[0][2]);
  acc[0][3] = fmaf(b.x, a.w, acc[0][3]);
  acc[1][0] = fmaf(b.y, a.x, acc[1][0]);
  acc[1][1] = fmaf(b.y, a.y, acc[1][1]);
  acc[1][2] = fmaf(b.y, a.z, acc[1][2]);
  acc[1][3] = fmaf(b.y, a.w, acc[1][3]);
  acc[2][0] = fmaf(b.z, a.x, acc[2][0]);
  acc[2][1] = fmaf(b.z, a.y, acc[2][1]);
  acc[2][2] = fmaf(b.z, a.z, acc[2][2]);
  acc[2][3] = fmaf(b.z, a.w, acc[2][3]);
  acc[3][0] = fmaf(b.w, a.x, acc[3][0]);
  acc[3][1] = fmaf(b.w, a.y, acc[3][1]);
  acc[3][2] = fmaf(b.w, a.z, acc[3][2]);
  acc[3][3] = fmaf(b.w, a.w, acc[3][3]);
}

// KPREP: block 24 zeros bnacc; blocks 0..23 build wqkvT bf16 blocked
// [kg(16)][n(384)][8k]  (B-fragment-native order)
__global__ __launch_bounds__(256) void kprep(
    const float* __restrict__ wqkv, bfu* __restrict__ wqkvT,
    float* __restrict__ bnacc) {
  int bid = blockIdx.x;
  if (bid == 24) {
    int t = threadIdx.x;
    bnacc[t] = 0.f;
    bnacc[256 + t] = 0.f;
    return;
  }
  int task = bid * 256 + threadIdx.x;  // kg*384 + n
  int kg = task / 384, n = task % 384;
  bfu tmp[8];
  #pragma unroll
  for (int j = 0; j < 8; ++j) tmp[j] = f2bf(wqkv[(kg * 8 + j) * 384 + n]);
  *(uint4*)&wqkvT[(size_t)kg * 3072 + n * 8] = *(const uint4*)tmp;
}

// K1: gather -> tok fp32 [reg][c][t]; aln bf16 blocked [reg][g=c/8][t][8c]
__global__ __launch_bounds__(256) void k1_gather(
    const float* __restrict__ x, const float* __restrict__ g,
    const float* __restrict__ bia, float* __restrict__ tok,
    bfu* __restrict__ aln) {
  int reg = blockIdx.x;
  int b = reg / NREGB, ij = reg % NREGB;
  int i = ij / NR, j = ij % NR;
  int t = threadIdx.x;
  int r = t >> 4, s = t & 15;
  int hh = i * STEP + r, ww = j * STEP + s;
  const float* xp = x + (size_t)b * DIMC * HW + (size_t)hh * WW_ + ww;
  float* tp = tok + (size_t)reg * DIMC * TT + t;
  float sum = 0.f, sq = 0.f;
  #pragma unroll 4
  for (int c = 0; c < DIMC; ++c) {
    float v = xp[(size_t)c * HW];
    tp[c * TT] = v;
    sum += v;
    sq = fmaf(v, v, sq);
  }
  float mu = sum * (1.0f / DIMC);
  float var = sq * (1.0f / DIMC) - mu * mu;
  float rstd = rsqrtf(var + 1e-5f);
  bfu* ap = aln + (size_t)reg * 32768 + t * 8;
  #pragma unroll
  for (int gidx = 0; gidx < 16; ++gidx) {
    bfu tmp[8];
    #pragma unroll
    for (int jj = 0; jj < 8; ++jj) {
      int c = gidx * 8 + jj;
      float vv = xp[(size_t)c * HW];  // L2-hot re-read
      tmp[jj] = f2bf((vv - mu) * rstd * g[c] + bia[c]);
    }
    *(uint4*)&ap[(size_t)gidx * 2048] = *(const uint4*)tmp;
  }
}

// K2: LDS-free register MFMA GEMM. Block=(reg, 64-token group), 4 waves.
__global__ __launch_bounds__(256) void k2_qkv(
    const bfu* __restrict__ aln, const bfu* __restrict__ wqkvT,
    bfu* __restrict__ qkvt) {
  int reg = blockIdx.x;
  int mt = blockIdx.y;
  int tid = threadIdx.x;
  int wave = tid >> 6, lane = tid & 63;
  int quad = lane >> 4, n16 = lane & 15;
  const bfu* ab = aln + (size_t)reg * 32768 + (mt * 64 + n16) * 8;
  const bfu* bb = wqkvT + (wave * 96 + n16) * 8;
  f32x4 acc[4][6];
  #pragma unroll
  for (int m = 0; m < 4; ++m)
    #pragma unroll
    for (int nt = 0; nt < 6; ++nt) acc[m][nt] = (f32x4){0.f, 0.f, 0.f, 0.f};
  #pragma unroll
  for (int ph = 0; ph < 4; ++ph) {
    int gg = ph * 4 + quad;
    bf16x8 af[4];
    #pragma unroll
    for (int m = 0; m < 4; ++m)
      af[m] = *(const bf16x8*)&ab[(size_t)gg * 2048 + m * 128];
    bf16x8 bfr[6];
    #pragma unroll
    for (int nt = 0; nt < 6; ++nt)
      bfr[nt] = *(const bf16x8*)&bb[(size_t)gg * 3072 + nt * 128];
    #pragma unroll
    for (int m = 0; m < 4; ++m)
      #pragma unroll
      for (int nt = 0; nt < 6; ++nt)
        acc[m][nt] =
            __builtin_amdgcn_mfma_f32_16x16x32_bf16(af[m], bfr[nt], acc[m][nt], 0, 0, 0);
  }
  bfu* outp =
      qkvt + ((size_t)reg * 256 + mt * 64 + quad * 4) * 384 + wave * 96 + n16;
  #pragma unroll
  for (int m = 0; m < 4; ++m)
    #pragma unroll
    for (int nt = 0; nt < 6; ++nt)
      #pragma unroll
      for (int r = 0; r < 4; ++r)
        outp[(m * 16 + r) * 384 + nt * 16] = f2bf(acc[m][nt][r]);
}

// K3: MFMA attention (unchanged)
__global__ __launch_bounds__(256, 2) void k3_attn(
    const bfu* __restrict__ qkvt, bfu* __restrict__ o) {
  int reg = blockIdx.x;
  int h = blockIdx.y;
  __shared__ __align__(16) bfu sVt[32 * 264];
  __shared__ __align__(16) bfu sP[4][16 * 264];
  int tid = threadIdx.x;
  int wave = tid >> 6, lane = tid & 63;
  int quad = lane >> 4, n16 = lane & 15;
  const bfu* qb = qkvt + (size_t)reg * 256 * 384;
  {
    const bfu* vrow = qb + tid * 384 + 256 + h * 32;
    #pragma unroll
    for (int dg = 0; dg < 8; ++dg) {
      ushort4 v4 = *(const ushort4*)(vrow + dg * 4);
      sVt[(dg * 4 + 0) * 264 + tid] = v4.x;
      sVt[(dg * 4 + 1) * 264 + tid] = v4.y;
      sVt[(dg * 4 + 2) * 264 + tid] = v4.z;
      sVt[(dg * 4 + 3) * 264 + tid] = v4.w;
    }
  }
  __syncthreads();
  bf16x8 vf[2][8];
  #pragma unroll
  for (int nt = 0; nt < 2; ++nt)
    #pragma unroll
    for (int kt = 0; kt < 8; ++kt)
      vf[nt][kt] = *(const bf16x8*)&sVt[(nt * 16 + n16) * 264 + kt * 32 + quad * 8];
  const bfu* kptr = qb + n16 * 384 + 128 + h * 32 + quad * 8;
  const f32x4 zero = {0.f, 0.f, 0.f, 0.f};
  const float scale = 0.17677669529663687f;
  bfu* pw = sP[wave];
  for (int mi = 0; mi < 4; ++mi) {
    int mt = wave * 4 + mi;
    bf16x8 qf = *(const bf16x8*)(qb + (mt * 16 + n16) * 384 + h * 32 + quad * 8);
    f32x4 st[16];
    #pragma unroll
    for (int T = 0; T < 16; ++T) {
      bf16x8 kf = *(const bf16x8*)(kptr + T * 16 * 384);
      st[T] = __builtin_amdgcn_mfma_f32_16x16x32_bf16(qf, kf, zero, 0, 0, 0);
    }
    float inv[4];
    #pragma unroll
    for (int r = 0; r < 4; ++r) {
      float m = st[0][r];
      #pragma unroll
      for (int T = 1; T < 16; ++T) m = fmaxf(m, st[T][r]);
      #pragma unroll
      for (int mk = 1; mk < 16; mk <<= 1) m = fmaxf(m, __shfl_xor(m, mk, 64));
      float l = 0.f;
      #pragma unroll
      for (int T = 0; T < 16; ++T) {
        float p = __expf((st[T][r] - m) * scale);
        st[T][r] = p;
        l += p;
      }
      #pragma unroll
      for (int mk = 1; mk < 16; mk <<= 1) l += __shfl_xor(l, mk, 64);
      inv[r] = 1.0f / l;
    }
    #pragma unroll
    for (int T = 0; T < 16; ++T) {
      #pragma unroll
      for (int r = 0; r < 4; ++r)
        pw[(quad * 4 + r) * 264 + T * 16 + n16] = f2bf(st[T][r]);
    }
    __builtin_amdgcn_wave_barrier();
    f32x4 oa0 = zero, oa1 = zero;
    #pragma unroll
    for (int kt = 0; kt < 8; ++kt) {
      bf16x8 pf = *(const bf16x8*)&pw[n16 * 264 + kt * 32 + quad * 8];
      oa0 = __builtin_amdgcn_mfma_f32_16x16x32_bf16(pf, vf[0][kt], oa0, 0, 0, 0);
      oa1 = __builtin_amdgcn_mfma_f32_16x16x32_bf16(pf, vf[1][kt], oa1, 0, 0, 0);
    }
    __builtin_amdgcn_wave_barrier();
    bfu* ob = o + ((size_t)reg * 256 + mt * 16 + quad * 4) * 128 + h * 32 + n16;
    #pragma unroll
    for (int r = 0; r < 4; ++r) {
      ob[r * 128] = f2bf(oa0[r] * inv[r]);
      ob[r * 128 + 16] = f2bf(oa1[r] * inv[r]);
    }
  }
}

// K4: tok[c][t] += o @ w_out + b_out (o token-major, LDS transpose)
__global__ __launch_bounds__(256) void k4_outproj(
    const bfu* __restrict__ o, const float* __restrict__ wout,
    const float* __restrict__ bout, float* __restrict__ tok) {
  int reg = blockIdx.x;
  int ct = blockIdx.y >> 2, tt = blockIdx.y & 3;
  __shared__ float As[128 * 64];
  __shared__ float Bs[64 * 68];
  int tid = threadIdx.x;
  for (int idx = tid; idx < 8192; idx += 256) {
    int k = idx >> 6, l = idx & 63;
    As[idx] = wout[k * 128 + ct * 64 + l];
  }
  int ti = tid & 15, tj = tid >> 4;
  float acc[4][4] = {};
  const bfu* ob = o + (size_t)reg * 256 * 128;
  for (int ph = 0; ph < 2; ++ph) {
    __syncthreads();
    for (int idx = tid; idx < 4096; idx += 256) {
      int l = idx >> 6, k = idx & 63;
      Bs[k * 68 + l] = bf2f(ob[(tt * 64 + l) * 128 + ph * 64 + k]);
    }
    __syncthreads();
    #pragma unroll 8
    for (int k = 0; k < 64; ++k) {
      float4 a = *(const float4*)&Bs[k * 68 + ti * 4];
      float4 bb = *(const float4*)&As[(ph * 64 + k) * 64 + tj * 4];
      fma4x4(a, bb, acc);
    }
  }
  float* tokr = tok + (size_t)reg * DIMC * TT;
  #pragma unroll
  for (int jj = 0; jj < 4; ++jj) {
    int c = ct * 64 + tj * 4 + jj;
    float bo = bout[c];
    float4 res = *(const float4*)&tokr[c * TT + tt * 64 + ti * 4];
    res.x += acc[jj][0] + bo;
    res.y += acc[jj][1] + bo;
    res.z += acc[jj][2] + bo;
    res.w += acc[jj][3] + bo;
    *(float4*)&tokr[c * TT + tt * 64 + ti * 4] = res;
  }
}

// K5: overlap-average merge + fused LN2 stats.
// Block = (hh, b), 512 threads: tid = q*128 + w; thread merges 32 channels
// (c = q*32..) for pixel w, accumulates partial LN2 sums; 4-way LDS reduce.
__global__ __launch_bounds__(512) void k5_merge(
    const float* __restrict__ tok, float* __restrict__ xf,
    float* __restrict__ mu2, float* __restrict__ rstd2) {
  int hh = blockIdx.x, b = blockIdx.y;
  int tid = threadIdx.x;
  int w = tid & 127, q = tid >> 7;
  int ilo = (hh >= 2) ? (hh - 2) / 14 : 0;
  int ihi = hh / 14;
  if (ihi > 8) ihi = 8;
  int jlo = (w >= 2) ? (w - 2) / 14 : 0;
  int jhi = w / 14;
  if (jhi > 8) jhi = 8;
  float rcnt = 1.0f / (float)((ihi - ilo + 1) * (jhi - jlo + 1));
  size_t offs[4];
  int nij = 0;
  for (int i = ilo; i <= ihi; ++i)
    for (int j = jlo; j <= jhi; ++j) {
      int reg = b * NREGB + i * NR + j;
      int r = hh - i * STEP, s = w - j * STEP;
      offs[nij++] = (size_t)reg * DIMC * TT + r * 16 + s;
    }
  float* xp = xf + ((size_t)b * DIMC << 14) + hh * WW_ + w;
  float sum = 0.f, sq = 0.f;
  int c0 = q * 32;
  for (int cc = 0; cc < 32; ++cc) {
    int c = c0 + cc;
    float s = 0.f;
    for (int k = 0; k < nij; ++k) s += tok[offs[k] + c * TT];
    float m = s * rcnt;
    xp[(size_t)c << 14] = m;
    sum += m;
    sq = fmaf(m, m, sq);
  }
  __shared__ float rs[512];
  __shared__ float rq[512];
  rs[tid] = sum;
  rq[tid] = sq;
  __syncthreads();
  if (tid < 128) {
    float s4 = rs[tid] + rs[tid + 128] + rs[tid + 256] + rs[tid + 384];
    float q4 = rq[tid] + rq[tid + 128] + rq[tid + 256] + rq[tid + 384];
    float mu = s4 * (1.0f / DIMC);
    float var = q4 * (1.0f / DIMC) - mu * mu;
    int pg = (b << 14) + hh * WW_ + tid;
    mu2[pg] = mu;
    rstd2[pg] = rsqrtf(var + 1e-5f);
  }
}

// K6: ym = LN2(xf) @ w_p0 + b_p0 -> bf16 [b][f][p]
__global__ __launch_bounds__(256) void k6_p0(
    const float* __restrict__ xf, const float* __restrict__ mu2,
    const float* __restrict__ rstd2, const float* __restrict__ g,
    const float* __restrict__ bia, const float* __restrict__ wp0,
    const float* __restrict__ bp0, bfu* __restrict__ ym) {
  int pt = blockIdx.x, ft = blockIdx.y, b = blockIdx.z;
  __shared__ float As[128 * 64];
  __shared__ float Bs[128 * 64];
  int tid = threadIdx.x;
  for (int idx = tid; idx < 8192; idx += 256) {
    int c = idx >> 6, l = idx & 63;
    int p = pt * 64 + l;
    float v = xf[((size_t)(b * DIMC + c) << 14) + p];
    As[idx] = (v - mu2[(b << 14) + p]) * rstd2[(b << 14) + p] * g[c] + bia[c];
    Bs[idx] = wp0[c * HID + ft * 64 + l];
  }
  __syncthreads();
  int ti = tid & 15, tj = tid >> 4;
  float acc[4][4] = {};
  #pragma unroll 8
  for (int k = 0; k < 128; ++k) {
    float4 a = *(const float4*)&As[k * 64 + ti * 4];
    float4 bb = *(const float4*)&Bs[k * 64 + tj * 4];
    fma4x4(a, bb, acc);
  }
  #pragma unroll
  for (int jj = 0; jj < 4; ++jj) {
    int f = ft * 64 + tj * 4 + jj;
    float bo = bp0[f];
    ushort4 pk;
    pk.x = f2bf(acc[jj][0] + bo);
    pk.y = f2bf(acc[jj][1] + bo);
    pk.z = f2bf(acc[jj][2] + bo);
    pk.w = f2bf(acc[jj][3] + bo);
    *(ushort4*)&ym[((size_t)(b * HID + f) << 14) + pt * 64 + ti * 4] = pk;
  }
}

// K7: 5x5 depthwise conv, whole plane in LDS, fused BN partials
__global__ __launch_bounds__(256) void k7_conv(
    const bfu* __restrict__ ym, const float* __restrict__ dwk,
    bfu* __restrict__ ym2, float* __restrict__ bnacc) {
  int bf = blockIdx.x;
  int f = bf & (HID - 1);
  __shared__ bfu sp[128 * 134];
  const bfu* in = ym + ((size_t)bf << 14);
  int tid = threadIdx.x;
  for (int idx = tid; idx < 2048; idx += 256) {
    int r = idx >> 4, c8 = (idx & 15) << 3;
    ushort4 a = *(const ushort4*)&in[(r << 7) + c8];
    ushort4 b = *(const ushort4*)&in[(r << 7) + c8 + 4];
    bfu* d = &sp[r * 134 + c8];
    d[0] = a.x; d[1] = a.y; d[2] = a.z; d[3] = a.w;
    d[4] = b.x; d[5] = b.y; d[6] = b.z; d[7] = b.w;
  }
  float wk[25];
  #pragma unroll
  for (int i = 0; i < 25; ++i) wk[i] = dwk[f * 25 + i];
  __syncthreads();
  int row = tid >> 1, half = (tid & 1) << 6;
  float acc[64];
  #pragma unroll
  for (int i = 0; i < 64; ++i) acc[i] = 0.f;
  #pragma unroll
  for (int ky = 0; ky < 5; ++ky) {
    int y = row + ky - 2;
    if (y < 0 || y >= 128) continue;
    const bfu* rp = &sp[y * 134];
    float win[68];
    #pragma unroll
    for (int c = 0; c < 68; ++c) {
      int cc = half + c - 2;
      win[c] = (cc >= 0 && cc < 128) ? bf2f(rp[cc]) : 0.f;
    }
    #pragma unroll
    for (int kx = 0; kx < 5; ++kx) {
      float wv = wk[ky * 5 + kx];
      #pragma unroll
      for (int i = 0; i < 64; ++i) acc[i] = fmaf(win[i + kx], wv, acc[i]);
    }
  }
  float s = 0.f, sq = 0.f;
  #pragma unroll
  for (int i = 0; i < 64; ++i) {
    s += acc[i];
    sq = fmaf(acc[i], acc[i], sq);
  }
  bfu* op = ym2 + ((size_t)bf << 14) + (row << 7) + half;
  #pragma unroll
  for (int g8 = 0; g8 < 8; ++g8) {
    bfu tmp[8];
    #pragma unroll
    for (int i = 0; i < 8; ++i) tmp[i] = f2bf(acc[g8 * 8 + i]);
    *(uint4*)&op[g8 * 8] = *(const uint4*)tmp;
  }
  __syncthreads();
  float* red = (float*)sp;
  red[tid] = s;
  red[256 + tid] = sq;
  __syncthreads();
  for (int o = 128; o > 0; o >>= 1) {
    if (tid < o) {
      red[tid] += red[tid + o];
      red[256 + tid] += red[256 + tid + o];
    }
    __syncthreads();
  }
  if (tid == 0) {
    atomicAdd(&bnacc[f], red[0]);
    atomicAdd(&bnacc[HID + f], red[256]);
  }
}

// K8: finalize BN stats
__global__ __launch_bounds__(256) void k8_fin(
    const float* __restrict__ bnacc, float* __restrict__ bnm,
    float* __restrict__ bnr) {
  int f = threadIdx.x;
  float mu = bnacc[f] * (1.0f / 65536.f);
  float var = bnacc[HID + f] * (1.0f / 65536.f) - mu * mu;
  bnm[f] = mu;
  bnr[f] = rsqrtf(var + 1e-5f);
}

// K9: g2 = gelu(gelu(bn(ym2)))
__global__ __launch_bounds__(256) void k9_act(
    const bfu* __restrict__ ym2, const float* __restrict__ bnm,
    const float* __restrict__ bnr, const float* __restrict__ g,
    const float* __restrict__ bia, bfu* __restrict__ g2) {
  int base = (blockIdx.x * 256 + threadIdx.x) * 4;
  int f = (base >> 14) & (HID - 1);
  float mean = bnm[f];
  float sc = bnr[f] * g[f];
  float bb = bia[f];
  ushort4 rv = *(const ushort4*)&ym2[base];
  float v0 = (bf2f(rv.x) - mean) * sc + bb;
  float v1 = (bf2f(rv.y) - mean) * sc + bb;
  float v2 = (bf2f(rv.z) - mean) * sc + bb;
  float v3 = (bf2f(rv.w) - mean) * sc + bb;
  v0 = gelu_exact(gelu_exact(v0));
  v1 = gelu_exact(gelu_exact(v1));
  v2 = gelu_exact(gelu_exact(v2));
  v3 = gelu_exact(gelu_exact(v3));
  ushort4 pk;
  pk.x = f2bf(v0);
  pk.y = f2bf(v1);
  pk.z = f2bf(v2);
  pk.w = f2bf(v3);
  *(ushort4*)&g2[base] = pk;
}

// K10: out = g2 @ w_p2 + b_p2 + xf
__global__ __launch_bounds__(256) void k10_p2(
    const bfu* __restrict__ g2, const float* __restrict__ wp2,
    const float* __restrict__ bp2, const float* __restrict__ xf,
    float* __restrict__ outp) {
  int pt = blockIdx.x, ct = blockIdx.y, b = blockIdx.z;
  __shared__ float As[128 * 64];
  __shared__ float Bs[128 * 64];
  int tid = threadIdx.x;
  int ti = tid & 15, tj = tid >> 4;
  float acc[4][4] = {};
  for (int kt = 0; kt < 2; ++kt) {
    for (int idx = tid; idx < 8192; idx += 256) {
      int k = idx >> 6, l = idx & 63;
      int f = kt * 128 + k;
      As[idx] = bf2f(g2[((size_t)(b * HID + f) << 14) + pt * 64 + l]);
      Bs[idx] = wp2[f * DIMC + ct * 64 + l];
    }
    __syncthreads();
    #pragma unroll 8
    for (int k = 0; k < 128; ++k) {
      float4 a = *(const float4*)&As[k * 64 + ti * 4];
      float4 bb = *(const float4*)&Bs[k * 64 + tj * 4];
      fma4x4(a, bb, acc);
    }
    __syncthreads();
  }
  #pragma unroll
  for (int jj = 0; jj < 4; ++jj) {
    int c = ct * 64 + tj * 4 + jj;
    float bo = bp2[c];
    size_t off = ((size_t)(b * DIMC + c) << 14) + pt * 64 + ti * 4;
    float4 res = *(const float4*)&xf[off];
    res.x += acc[jj][0] + bo;
    res.y += acc[jj][1] + bo;
    res.z += acc[jj][2] + bo;
    res.w += acc[jj][3] + bo;
    *(float4*)&outp[off] = res;
  }
}

extern "C" void kernel_launch(void* const* d_in, const int* in_sizes, int n_in,
                              void* d_out, int out_size, void* d_ws,
                              size_t ws_size, hipStream_t stream) {
  const float* x = (const float*)d_in[0];
  const float* ln1_g = (const float*)d_in[1];
  const float* ln1_b = (const float*)d_in[2];
  const float* w_qkv = (const float*)d_in[3];
  const float* w_out = (const float*)d_in[4];
  const float* b_out = (const float*)d_in[5];
  const float* ln2_g = (const float*)d_in[6];
  const float* ln2_b = (const float*)d_in[7];
  const float* w_p0 = (const float*)d_in[8];
  const float* b_p0 = (const float*)d_in[9];
  const float* dw_k = (const float*)d_in[10];
  const float* bn_g = (const float*)d_in[11];
  const float* bn_b = (const float*)d_in[12];
  const float* w_p2 = (const float*)d_in[13];
  const float* b_p2 = (const float*)d_in[14];
  float* outp = (float*)d_out;

  char* ws = (char*)d_ws;
  size_t off = 0;
  auto alloc = [&](size_t bytes) {
    void* p = ws + off;
    off += (bytes + 1023) & ~(size_t)1023;
    return p;
  };
  float* tok = (float*)alloc((size_t)NREG * DIMC * TT * 4);
  bfu* qkvt = (bfu*)alloc((size_t)NREG * 384 * TT * 2);
  float* xf = (float*)alloc((size_t)BB * DIMC * HW * 4);
  float* mu2 = (float*)alloc((size_t)BB * HW * 4);
  float* rstd2 = (float*)alloc((size_t)BB * HW * 4);
  bfu* ym = (bfu*)alloc((size_t)BB * HID * HW * 2);
  bfu* ym2 = (bfu*)alloc((size_t)BB * HID * HW * 2);
  float* bnacc = (float*)alloc(2 * HID * 4);
  float* bnm = (float*)alloc(HID * 4);
  float* bnr = (float*)alloc(HID * 4);
  bfu* wqkvT = (bfu*)alloc(16 * 3072 * 2);
  // overlays (lifetimes disjoint)
  bfu* o = ym;     // used k3->k4; ym written first in k6
  bfu* aln = ym2;  // used k1->k2; ym2 written first in k7

  kprep<<<25, 256, 0, stream>>>(w_qkv, wqkvT, bnacc);
  k1_gather<<<NREG, 256, 0, stream>>>(x, ln1_g, ln1_b, tok, aln);
  k2_qkv<<<dim3(NREG, 4), 256, 0, stream>>>(aln, wqkvT, qkvt);
  k3_attn<<<dim3(NREG, NHEADS), 256, 0, stream>>>(qkvt, o);
  k4_outproj<<<dim3(NREG, 8), 256, 0, stream>>>(o, w_out, b_out, tok);
  k5_merge<<<dim3(HH_, BB), 512, 0, stream>>>(tok, xf, mu2, rstd2);
  k6_p0<<<dim3(256, 4, BB), 256, 0, stream>>>(xf, mu2, rstd2, ln2_g, ln2_b,
                                              w_p0, b_p0, ym);
  k7_conv<<<BB * HID, 256, 0, stream>>>(ym, dw_k, ym2, bnacc);
  k8_fin<<<1, 256, 0, stream>>>(bnacc, bnm, bnr);
  k9_act<<<16384, 256, 0, stream>>>(ym2, bnm, bnr, bn_g, bn_b, ym);
  k10_p2<<<dim3(256, 2, BB), 256, 0, stream>>>(ym, w_p2, b_p2, xf, outp);
}

// Round 6
// 440.141 us; speedup vs baseline: 1.3924x; 1.2019x over previous
//
#include <hip/hip_runtime.h>

#define DIMC 128
#define NHEADS 4
#define HD 32
#define HID 256
#define BB 4
#define HH_ 128
#define WW_ 128
#define HW 16384
#define RS 16
#define STEP 14
#define NR 9
#define NREGB 81
#define NREG 324
#define TT 256

typedef unsigned short bfu;  // bf16 bits
typedef __attribute__((ext_vector_type(8))) short bf16x8;
typedef __attribute__((ext_vector_type(4))) float f32x4;

__device__ __forceinline__ float bf2f(bfu u) {
  return __uint_as_float(((unsigned int)u) << 16);
}
__device__ __forceinline__ bfu f2bf(float f) {
  unsigned int i = __float_as_uint(f);
  unsigned int r = i + 0x7fffu + ((i >> 16) & 1u);
  return (bfu)(r >> 16);
}
__device__ __forceinline__ float gelu_exact(float x) {
  return 0.5f * x * (1.0f + erff(x * 0.70710678118654752f));
}
__device__ __forceinline__ void fma4x4(const float4 a, const float4 b, float acc[4][4]) {
  acc[0][0] = fmaf(b.x, a.x, acc[0][0]);
  acc[0][1] = fmaf(b.x, a.y, acc[0][1]);
  acc[0][2] = fmaf(b.x, a.z, acc[0][2]);
  acc[0][3] = fmaf(b.x, a.w, acc[0][3]);
  acc[1][0] = fmaf(b.y, a.x, acc[1][0]);
  acc[1][1] = fmaf(b.y, a.y, acc[1][1]);
  acc[1][2] = fmaf(b.y, a.z, acc[1][2]);
  acc[1][3] = fmaf(b.y, a.w, acc[1][3]);
  acc[2][0] = fmaf(b.z, a.x, acc[2][0]);
  acc[2][1] = fmaf(b.z, a.y, acc[2][1]);
  acc[2][2] = fmaf(b.z, a.z, acc[2][2]);
  acc[2][3] = fmaf(b.z, a.w, acc[2][3]);
  acc[3][0] = fmaf(b.w, a.x, acc[3][0]);
  acc[3][1] = fmaf(b.w, a.y, acc[3][1]);
  acc[3][2] = fmaf(b.w, a.z, acc[3][2]);
  acc[3][3] = fmaf(b.w, a.w, acc[3][3]);
}

// KPREP: bid 0..23 wqkvT [kg16][n384][8k]; bid 24 zero bnacc;
// bid 25..40 ap0 = w_p0^T blocked [kg16][f256][8k];
// bid 41..56 ap2 = w_p2^T blocked [kg32][c128][8k]
__global__ __launch_bounds__(256) void kprep(
    const float* __restrict__ wqkv, const float* __restrict__ wp0,
    const float* __restrict__ wp2, bfu* __restrict__ wqkvT,
    bfu* __restrict__ ap0, bfu* __restrict__ ap2, float* __restrict__ bnacc) {
  int bid = blockIdx.x;
  int tid = threadIdx.x;
  if (bid < 24) {
    int task = bid * 256 + tid;  // kg*384 + n
    int kg = task / 384, n = task % 384;
    bfu tmp[8];
    #pragma unroll
    for (int j = 0; j < 8; ++j) tmp[j] = f2bf(wqkv[(kg * 8 + j) * 384 + n]);
    *(uint4*)&wqkvT[(size_t)kg * 3072 + n * 8] = *(const uint4*)tmp;
  } else if (bid == 24) {
    bnacc[tid] = 0.f;
    bnacc[256 + tid] = 0.f;
  } else if (bid < 41) {
    int task = (bid - 25) * 256 + tid;  // kg*256 + f
    int kg = task >> 8, f = task & 255;
    bfu tmp[8];
    #pragma unroll
    for (int j = 0; j < 8; ++j) tmp[j] = f2bf(wp0[(kg * 8 + j) * 256 + f]);
    *(uint4*)&ap0[((size_t)kg * 256 + f) * 8] = *(const uint4*)tmp;
  } else {
    int task = (bid - 41) * 256 + tid;  // kg*128 + c
    int kg = task >> 7, c = task & 127;
    bfu tmp[8];
    #pragma unroll
    for (int j = 0; j < 8; ++j) tmp[j] = f2bf(wp2[(kg * 8 + j) * 128 + c]);
    *(uint4*)&ap2[((size_t)kg * 128 + c) * 8] = *(const uint4*)tmp;
  }
}

// K1: gather -> tok fp32 [reg][c][t]; aln bf16 blocked [reg][g=c/8][t][8c]
__global__ __launch_bounds__(256) void k1_gather(
    const float* __restrict__ x, const float* __restrict__ g,
    const float* __restrict__ bia, float* __restrict__ tok,
    bfu* __restrict__ aln) {
  int reg = blockIdx.x;
  int b = reg / NREGB, ij = reg % NREGB;
  int i = ij / NR, j = ij % NR;
  int t = threadIdx.x;
  int r = t >> 4, s = t & 15;
  int hh = i * STEP + r, ww = j * STEP + s;
  const float* xp = x + (size_t)b * DIMC * HW + (size_t)hh * WW_ + ww;
  float* tp = tok + (size_t)reg * DIMC * TT + t;
  float sum = 0.f, sq = 0.f;
  #pragma unroll 4
  for (int c = 0; c < DIMC; ++c) {
    float v = xp[(size_t)c * HW];
    tp[c * TT] = v;
    sum += v;
    sq = fmaf(v, v, sq);
  }
  float mu = sum * (1.0f / DIMC);
  float var = sq * (1.0f / DIMC) - mu * mu;
  float rstd = rsqrtf(var + 1e-5f);
  bfu* ap = aln + (size_t)reg * 32768 + t * 8;
  #pragma unroll
  for (int gidx = 0; gidx < 16; ++gidx) {
    bfu tmp[8];
    #pragma unroll
    for (int jj = 0; jj < 8; ++jj) {
      int c = gidx * 8 + jj;
      float vv = xp[(size_t)c * HW];  // L2-hot re-read
      tmp[jj] = f2bf((vv - mu) * rstd * g[c] + bia[c]);
    }
    *(uint4*)&ap[(size_t)gidx * 2048] = *(const uint4*)tmp;
  }
}

// K2: LDS-free register MFMA GEMM (qkv)
__global__ __launch_bounds__(256) void k2_qkv(
    const bfu* __restrict__ aln, const bfu* __restrict__ wqkvT,
    bfu* __restrict__ qkvt) {
  int reg = blockIdx.x;
  int mt = blockIdx.y;
  int tid = threadIdx.x;
  int wave = tid >> 6, lane = tid & 63;
  int quad = lane >> 4, n16 = lane & 15;
  const bfu* ab = aln + (size_t)reg * 32768 + (mt * 64 + n16) * 8;
  const bfu* bb = wqkvT + (wave * 96 + n16) * 8;
  f32x4 acc[4][6];
  #pragma unroll
  for (int m = 0; m < 4; ++m)
    #pragma unroll
    for (int nt = 0; nt < 6; ++nt) acc[m][nt] = (f32x4){0.f, 0.f, 0.f, 0.f};
  #pragma unroll
  for (int ph = 0; ph < 4; ++ph) {
    int gg = ph * 4 + quad;
    bf16x8 af[4];
    #pragma unroll
    for (int m = 0; m < 4; ++m)
      af[m] = *(const bf16x8*)&ab[(size_t)gg * 2048 + m * 128];
    bf16x8 bfr[6];
    #pragma unroll
    for (int nt = 0; nt < 6; ++nt)
      bfr[nt] = *(const bf16x8*)&bb[(size_t)gg * 3072 + nt * 128];
    #pragma unroll
    for (int m = 0; m < 4; ++m)
      #pragma unroll
      for (int nt = 0; nt < 6; ++nt)
        acc[m][nt] =
            __builtin_amdgcn_mfma_f32_16x16x32_bf16(af[m], bfr[nt], acc[m][nt], 0, 0, 0);
  }
  bfu* outp =
      qkvt + ((size_t)reg * 256 + mt * 64 + quad * 4) * 384 + wave * 96 + n16;
  #pragma unroll
  for (int m = 0; m < 4; ++m)
    #pragma unroll
    for (int nt = 0; nt < 6; ++nt)
      #pragma unroll
      for (int r = 0; r < 4; ++r)
        outp[(m * 16 + r) * 384 + nt * 16] = f2bf(acc[m][nt][r]);
}

// K3: MFMA attention (unchanged)
__global__ __launch_bounds__(256, 2) void k3_attn(
    const bfu* __restrict__ qkvt, bfu* __restrict__ o) {
  int reg = blockIdx.x;
  int h = blockIdx.y;
  __shared__ __align__(16) bfu sVt[32 * 264];
  __shared__ __align__(16) bfu sP[4][16 * 264];
  int tid = threadIdx.x;
  int wave = tid >> 6, lane = tid & 63;
  int quad = lane >> 4, n16 = lane & 15;
  const bfu* qb = qkvt + (size_t)reg * 256 * 384;
  {
    const bfu* vrow = qb + tid * 384 + 256 + h * 32;
    #pragma unroll
    for (int dg = 0; dg < 8; ++dg) {
      ushort4 v4 = *(const ushort4*)(vrow + dg * 4);
      sVt[(dg * 4 + 0) * 264 + tid] = v4.x;
      sVt[(dg * 4 + 1) * 264 + tid] = v4.y;
      sVt[(dg * 4 + 2) * 264 + tid] = v4.z;
      sVt[(dg * 4 + 3) * 264 + tid] = v4.w;
    }
  }
  __syncthreads();
  bf16x8 vf[2][8];
  #pragma unroll
  for (int nt = 0; nt < 2; ++nt)
    #pragma unroll
    for (int kt = 0; kt < 8; ++kt)
      vf[nt][kt] = *(const bf16x8*)&sVt[(nt * 16 + n16) * 264 + kt * 32 + quad * 8];
  const bfu* kptr = qb + n16 * 384 + 128 + h * 32 + quad * 8;
  const f32x4 zero = {0.f, 0.f, 0.f, 0.f};
  const float scale = 0.17677669529663687f;
  bfu* pw = sP[wave];
  for (int mi = 0; mi < 4; ++mi) {
    int mt = wave * 4 + mi;
    bf16x8 qf = *(const bf16x8*)(qb + (mt * 16 + n16) * 384 + h * 32 + quad * 8);
    f32x4 st[16];
    #pragma unroll
    for (int T = 0; T < 16; ++T) {
      bf16x8 kf = *(const bf16x8*)(kptr + T * 16 * 384);
      st[T] = __builtin_amdgcn_mfma_f32_16x16x32_bf16(qf, kf, zero, 0, 0, 0);
    }
    float inv[4];
    #pragma unroll
    for (int r = 0; r < 4; ++r) {
      float m = st[0][r];
      #pragma unroll
      for (int T = 1; T < 16; ++T) m = fmaxf(m, st[T][r]);
      #pragma unroll
      for (int mk = 1; mk < 16; mk <<= 1) m = fmaxf(m, __shfl_xor(m, mk, 64));
      float l = 0.f;
      #pragma unroll
      for (int T = 0; T < 16; ++T) {
        float p = __expf((st[T][r] - m) * scale);
        st[T][r] = p;
        l += p;
      }
      #pragma unroll
      for (int mk = 1; mk < 16; mk <<= 1) l += __shfl_xor(l, mk, 64);
      inv[r] = 1.0f / l;
    }
    #pragma unroll
    for (int T = 0; T < 16; ++T) {
      #pragma unroll
      for (int r = 0; r < 4; ++r)
        pw[(quad * 4 + r) * 264 + T * 16 + n16] = f2bf(st[T][r]);
    }
    __builtin_amdgcn_wave_barrier();
    f32x4 oa0 = zero, oa1 = zero;
    #pragma unroll
    for (int kt = 0; kt < 8; ++kt) {
      bf16x8 pf = *(const bf16x8*)&pw[n16 * 264 + kt * 32 + quad * 8];
      oa0 = __builtin_amdgcn_mfma_f32_16x16x32_bf16(pf, vf[0][kt], oa0, 0, 0, 0);
      oa1 = __builtin_amdgcn_mfma_f32_16x16x32_bf16(pf, vf[1][kt], oa1, 0, 0, 0);
    }
    __builtin_amdgcn_wave_barrier();
    bfu* ob = o + ((size_t)reg * 256 + mt * 16 + quad * 4) * 128 + h * 32 + n16;
    #pragma unroll
    for (int r = 0; r < 4; ++r) {
      ob[r * 128] = f2bf(oa0[r] * inv[r]);
      ob[r * 128 + 16] = f2bf(oa1[r] * inv[r]);
    }
  }
}

// K4: tok[c][t] += o @ w_out + b_out (o token-major, LDS transpose)
__global__ __launch_bounds__(256) void k4_outproj(
    const bfu* __restrict__ o, const float* __restrict__ wout,
    const float* __restrict__ bout, float* __restrict__ tok) {
  int reg = blockIdx.x;
  int ct = blockIdx.y >> 2, tt = blockIdx.y & 3;
  __shared__ float As[128 * 64];
  __shared__ float Bs[64 * 68];
  int tid = threadIdx.x;
  for (int idx = tid; idx < 8192; idx += 256) {
    int k = idx >> 6, l = idx & 63;
    As[idx] = wout[k * 128 + ct * 64 + l];
  }
  int ti = tid & 15, tj = tid >> 4;
  float acc[4][4] = {};
  const bfu* ob = o + (size_t)reg * 256 * 128;
  for (int ph = 0; ph < 2; ++ph) {
    __syncthreads();
    for (int idx = tid; idx < 4096; idx += 256) {
      int l = idx >> 6, k = idx & 63;
      Bs[k * 68 + l] = bf2f(ob[(tt * 64 + l) * 128 + ph * 64 + k]);
    }
    __syncthreads();
    #pragma unroll 8
    for (int k = 0; k < 64; ++k) {
      float4 a = *(const float4*)&Bs[k * 68 + ti * 4];
      float4 bb = *(const float4*)&As[(ph * 64 + k) * 64 + tj * 4];
      fma4x4(a, bb, acc);
    }
  }
  float* tokr = tok + (size_t)reg * DIMC * TT;
  #pragma unroll
  for (int jj = 0; jj < 4; ++jj) {
    int c = ct * 64 + tj * 4 + jj;
    float bo = bout[c];
    float4 res = *(const float4*)&tokr[c * TT + tt * 64 + ti * 4];
    res.x += acc[jj][0] + bo;
    res.y += acc[jj][1] + bo;
    res.z += acc[jj][2] + bo;
    res.w += acc[jj][3] + bo;
    *(float4*)&tokr[c * TT + tt * 64 + ti * 4] = res;
  }
}

// K5: overlap merge -> xf fp32 + xln = LN2'd bf16 blocked [b][cg][p][8c]
__global__ __launch_bounds__(512) void k5_merge(
    const float* __restrict__ tok, const float* __restrict__ ln2g,
    const float* __restrict__ ln2b, float* __restrict__ xf,
    bfu* __restrict__ xln) {
  int hh = blockIdx.x, b = blockIdx.y;
  int tid = threadIdx.x;
  int w = tid & 127, q = tid >> 7;
  int ilo = (hh >= 2) ? (hh - 2) / 14 : 0;
  int ihi = hh / 14;
  if (ihi > 8) ihi = 8;
  int jlo = (w >= 2) ? (w - 2) / 14 : 0;
  int jhi = w / 14;
  if (jhi > 8) jhi = 8;
  float rcnt = 1.0f / (float)((ihi - ilo + 1) * (jhi - jlo + 1));
  size_t offs[4];
  int nij = 0;
  for (int i = ilo; i <= ihi; ++i)
    for (int j = jlo; j <= jhi; ++j) {
      int reg = b * NREGB + i * NR + j;
      int r = hh - i * STEP, s = w - j * STEP;
      offs[nij++] = (size_t)reg * DIMC * TT + r * 16 + s;
    }
  float* xp = xf + ((size_t)b * DIMC << 14) + hh * WW_ + w;
  float mm[32];
  float sum = 0.f, sq = 0.f;
  int c0 = q * 32;
  for (int cc = 0; cc < 32; ++cc) {
    int c = c0 + cc;
    float s = 0.f;
    for (int k = 0; k < nij; ++k) s += tok[offs[k] + c * TT];
    float m = s * rcnt;
    xp[(size_t)c << 14] = m;
    mm[cc] = m;
    sum += m;
    sq = fmaf(m, m, sq);
  }
  __shared__ float rs[512];
  __shared__ float rq[512];
  __shared__ float muS[128];
  __shared__ float rsdS[128];
  rs[tid] = sum;
  rq[tid] = sq;
  __syncthreads();
  if (tid < 128) {
    float s4 = rs[tid] + rs[tid + 128] + rs[tid + 256] + rs[tid + 384];
    float q4 = rq[tid] + rq[tid + 128] + rq[tid + 256] + rq[tid + 384];
    float mu = s4 * (1.0f / DIMC);
    float var = q4 * (1.0f / DIMC) - mu * mu;
    muS[tid] = mu;
    rsdS[tid] = rsqrtf(var + 1e-5f);
  }
  __syncthreads();
  float mu = muS[w], rstd = rsdS[w];
  int p = hh * WW_ + w;
  #pragma unroll
  for (int gl = 0; gl < 4; ++gl) {
    int gidx = q * 4 + gl;
    bfu tmp[8];
    #pragma unroll
    for (int j = 0; j < 8; ++j) {
      int c = gidx * 8 + j;
      tmp[j] = f2bf((mm[gl * 8 + j] - mu) * rstd * ln2g[c] + ln2b[c]);
    }
    *(uint4*)&xln[(((size_t)(b * 16 + gidx) << 14) + p) * 8] = *(const uint4*)tmp;
  }
}

// K6: ym[b][f][p] = xln @ w_p0 + b_p0 via MFMA, A = w_p0^T (M=f), B = pixels
__global__ __launch_bounds__(256) void k6_p0(
    const bfu* __restrict__ xln, const bfu* __restrict__ ap0,
    const float* __restrict__ bp0, bfu* __restrict__ ym) {
  int b = blockIdx.y;
  int ptile = blockIdx.x * 64;
  int tid = threadIdx.x;
  int wv = tid >> 6, lane = tid & 63;
  int quad = lane >> 4, n16 = lane & 15;
  int p = ptile + wv * 16 + n16;
  f32x4 acc[16];
  #pragma unroll
  for (int mt = 0; mt < 16; ++mt) acc[mt] = (f32x4){0.f, 0.f, 0.f, 0.f};
  #pragma unroll
  for (int ph = 0; ph < 4; ++ph) {
    int gg = ph * 4 + quad;
    bf16x8 bfrag = *(const bf16x8*)&xln[(((size_t)(b * 16 + gg) << 14) + p) * 8];
    const bfu* arow = ap0 + ((size_t)gg * 256 + n16) * 8;
    #pragma unroll
    for (int mt = 0; mt < 16; ++mt) {
      bf16x8 afrag = *(const bf16x8*)&arow[mt * 128];
      acc[mt] = __builtin_amdgcn_mfma_f32_16x16x32_bf16(afrag, bfrag, acc[mt], 0, 0, 0);
    }
  }
  #pragma unroll
  for (int mt = 0; mt < 16; ++mt) {
    #pragma unroll
    for (int r = 0; r < 4; ++r) {
      int f = mt * 16 + quad * 4 + r;
      ym[((size_t)(b * HID + f) << 14) + p] = f2bf(acc[mt][r] + bp0[f]);
    }
  }
}

// K7: 5x5 depthwise conv, whole plane in LDS, fused BN partials
__global__ __launch_bounds__(256) void k7_conv(
    const bfu* __restrict__ ym, const float* __restrict__ dwk,
    bfu* __restrict__ ym2, float* __restrict__ bnacc) {
  int bf = blockIdx.x;
  int f = bf & (HID - 1);
  __shared__ bfu sp[128 * 134];
  const bfu* in = ym + ((size_t)bf << 14);
  int tid = threadIdx.x;
  for (int idx = tid; idx < 2048; idx += 256) {
    int r = idx >> 4, c8 = (idx & 15) << 3;
    ushort4 a = *(const ushort4*)&in[(r << 7) + c8];
    ushort4 b = *(const ushort4*)&in[(r << 7) + c8 + 4];
    bfu* d = &sp[r * 134 + c8];
    d[0] = a.x; d[1] = a.y; d[2] = a.z; d[3] = a.w;
    d[4] = b.x; d[5] = b.y; d[6] = b.z; d[7] = b.w;
  }
  float wk[25];
  #pragma unroll
  for (int i = 0; i < 25; ++i) wk[i] = dwk[f * 25 + i];
  __syncthreads();
  int row = tid >> 1, half = (tid & 1) << 6;
  float acc[64];
  #pragma unroll
  for (int i = 0; i < 64; ++i) acc[i] = 0.f;
  #pragma unroll
  for (int ky = 0; ky < 5; ++ky) {
    int y = row + ky - 2;
    if (y < 0 || y >= 128) continue;
    const bfu* rp = &sp[y * 134];
    float win[68];
    #pragma unroll
    for (int c = 0; c < 68; ++c) {
      int cc = half + c - 2;
      win[c] = (cc >= 0 && cc < 128) ? bf2f(rp[cc]) : 0.f;
    }
    #pragma unroll
    for (int kx = 0; kx < 5; ++kx) {
      float wv = wk[ky * 5 + kx];
      #pragma unroll
      for (int i = 0; i < 64; ++i) acc[i] = fmaf(win[i + kx], wv, acc[i]);
    }
  }
  float s = 0.f, sq = 0.f;
  #pragma unroll
  for (int i = 0; i < 64; ++i) {
    s += acc[i];
    sq = fmaf(acc[i], acc[i], sq);
  }
  bfu* op = ym2 + ((size_t)bf << 14) + (row << 7) + half;
  #pragma unroll
  for (int g8 = 0; g8 < 8; ++g8) {
    bfu tmp[8];
    #pragma unroll
    for (int i = 0; i < 8; ++i) tmp[i] = f2bf(acc[g8 * 8 + i]);
    *(uint4*)&op[g8 * 8] = *(const uint4*)tmp;
  }
  __syncthreads();
  float* red = (float*)sp;
  red[tid] = s;
  red[256 + tid] = sq;
  __syncthreads();
  for (int o = 128; o > 0; o >>= 1) {
    if (tid < o) {
      red[tid] += red[tid + o];
      red[256 + tid] += red[256 + tid + o];
    }
    __syncthreads();
  }
  if (tid == 0) {
    atomicAdd(&bnacc[f], red[0]);
    atomicAdd(&bnacc[HID + f], red[256]);
  }
}

// K8: finalize BN stats
__global__ __launch_bounds__(256) void k8_fin(
    const float* __restrict__ bnacc, float* __restrict__ bnm,
    float* __restrict__ bnr) {
  int f = threadIdx.x;
  float mu = bnacc[f] * (1.0f / 65536.f);
  float var = bnacc[HID + f] * (1.0f / 65536.f) - mu * mu;
  bnm[f] = mu;
  bnr[f] = rsqrtf(var + 1e-5f);
}

// K9: g2b = gelu(gelu(bn(ym2))) in blocked [b][fg][p][8f]
__global__ __launch_bounds__(256) void k9_act(
    const bfu* __restrict__ ym2, const float* __restrict__ bnm,
    const float* __restrict__ bnr, const float* __restrict__ g,
    const float* __restrict__ bia, bfu* __restrict__ g2b) {
  int idx = blockIdx.x * 256 + threadIdx.x;  // b*32*16384 + fg*16384 + p
  int p = idx & 16383;
  int fg = (idx >> 14) & 31;
  int b = idx >> 19;
  bfu tmp[8];
  #pragma unroll
  for (int i = 0; i < 8; ++i) {
    int f = fg * 8 + i;
    float v = bf2f(ym2[((size_t)(b * HID + f) << 14) + p]);
    v = (v - bnm[f]) * (bnr[f] * g[f]) + bia[f];
    tmp[i] = f2bf(gelu_exact(gelu_exact(v)));
  }
  *(uint4*)&g2b[(((size_t)(b * 32 + fg) << 14) + p) * 8] = *(const uint4*)tmp;
}

// K10: out = g2 @ w_p2 + b_p2 + xf via MFMA, A = w_p2^T (M=c), B = pixels
__global__ __launch_bounds__(256) void k10_p2(
    const bfu* __restrict__ g2b, const bfu* __restrict__ ap2,
    const float* __restrict__ bp2, const float* __restrict__ xf,
    float* __restrict__ outp) {
  int b = blockIdx.y;
  int ptile = blockIdx.x * 64;
  int tid = threadIdx.x;
  int wv = tid >> 6, lane = tid & 63;
  int quad = lane >> 4, n16 = lane & 15;
  int p = ptile + wv * 16 + n16;
  f32x4 acc[8];
  #pragma unroll
  for (int mt = 0; mt < 8; ++mt) acc[mt] = (f32x4){0.f, 0.f, 0.f, 0.f};
  #pragma unroll
  for (int ph = 0; ph < 8; ++ph) {
    int gg = ph * 4 + quad;
    bf16x8 bfrag = *(const bf16x8*)&g2b[(((size_t)(b * 32 + gg) << 14) + p) * 8];
    const bfu* arow = ap2 + ((size_t)gg * 128 + n16) * 8;
    #pragma unroll
    for (int mt = 0; mt < 8; ++mt) {
      bf16x8 afrag = *(const bf16x8*)&arow[mt * 128];
      acc[mt] = __builtin_amdgcn_mfma_f32_16x16x32_bf16(afrag, bfrag, acc[mt], 0, 0, 0);
    }
  }
  #pragma unroll
  for (int mt = 0; mt < 8; ++mt) {
    #pragma unroll
    for (int r = 0; r < 4; ++r) {
      int c = mt * 16 + quad * 4 + r;
      size_t off = ((size_t)(b * DIMC + c) << 14) + p;
      outp[off] = acc[mt][r] + bp2[c] + xf[off];
    }
  }
}

extern "C" void kernel_launch(void* const* d_in, const int* in_sizes, int n_in,
                              void* d_out, int out_size, void* d_ws,
                              size_t ws_size, hipStream_t stream) {
  const float* x = (const float*)d_in[0];
  const float* ln1_g = (const float*)d_in[1];
  const float* ln1_b = (const float*)d_in[2];
  const float* w_qkv = (const float*)d_in[3];
  const float* w_out = (const float*)d_in[4];
  const float* b_out = (const float*)d_in[5];
  const float* ln2_g = (const float*)d_in[6];
  const float* ln2_b = (const float*)d_in[7];
  const float* w_p0 = (const float*)d_in[8];
  const float* b_p0 = (const float*)d_in[9];
  const float* dw_k = (const float*)d_in[10];
  const float* bn_g = (const float*)d_in[11];
  const float* bn_b = (const float*)d_in[12];
  const float* w_p2 = (const float*)d_in[13];
  const float* b_p2 = (const float*)d_in[14];
  float* outp = (float*)d_out;

  char* ws = (char*)d_ws;
  size_t off = 0;
  auto alloc = [&](size_t bytes) {
    void* p = ws + off;
    off += (bytes + 1023) & ~(size_t)1023;
    return p;
  };
  float* tok = (float*)alloc((size_t)NREG * DIMC * TT * 4);
  bfu* qkvt = (bfu*)alloc((size_t)NREG * 384 * TT * 2);
  float* xf = (float*)alloc((size_t)BB * DIMC * HW * 4);
  bfu* xln = (bfu*)alloc((size_t)BB * DIMC * HW * 2);
  bfu* ym = (bfu*)alloc((size_t)BB * HID * HW * 2);
  bfu* ym2 = (bfu*)alloc((size_t)BB * HID * HW * 2);
  float* bnacc = (float*)alloc(2 * HID * 4);
  float* bnm = (float*)alloc(HID * 4);
  float* bnr = (float*)alloc(HID * 4);
  bfu* wqkvT = (bfu*)alloc(16 * 3072 * 2);
  bfu* ap0 = (bfu*)alloc(16 * 256 * 8 * 2);
  bfu* ap2 = (bfu*)alloc(32 * 128 * 8 * 2);
  // overlays (lifetimes disjoint)
  bfu* o = ym;     // used k3->k4; ym written first in k6
  bfu* aln = ym2;  // used k1->k2; ym2 written first in k7
  bfu* g2b = ym;   // used k9->k10; ym consumed by k7 before k9

  kprep<<<57, 256, 0, stream>>>(w_qkv, w_p0, w_p2, wqkvT, ap0, ap2, bnacc);
  k1_gather<<<NREG, 256, 0, stream>>>(x, ln1_g, ln1_b, tok, aln);
  k2_qkv<<<dim3(NREG, 4), 256, 0, stream>>>(aln, wqkvT, qkvt);
  k3_attn<<<dim3(NREG, NHEADS), 256, 0, stream>>>(qkvt, o);
  k4_outproj<<<dim3(NREG, 8), 256, 0, stream>>>(o, w_out, b_out, tok);
  k5_merge<<<dim3(HH_, BB), 512, 0, stream>>>(tok, ln2_g, ln2_b, xf, xln);
  k6_p0<<<dim3(256, BB), 256, 0, stream>>>(xln, ap0, b_p0, ym);
  k7_conv<<<BB * HID, 256, 0, stream>>>(ym, dw_k, ym2, bnacc);
  k8_fin<<<1, 256, 0, stream>>>(bnacc, bnm, bnr);
  k9_act<<<8192, 256, 0, stream>>>(ym2, bnm, bnr, bn_g, bn_b, g2b);
  k10_p2<<<dim3(256, BB), 256, 0, stream>>>(g2b, ap2, b_p2, xf, outp);
}

// Round 7
// 427.349 us; speedup vs baseline: 1.4341x; 1.0299x over previous
//
#include <hip/hip_runtime.h>

#define DIMC 128
#define NHEADS 4
#define HD 32
#define HID 256
#define BB 4
#define HH_ 128
#define WW_ 128
#define HW 16384
#define RS 16
#define STEP 14
#define NR 9
#define NREGB 81
#define NREG 324
#define TT 256

typedef unsigned short bfu;  // bf16 bits
typedef __attribute__((ext_vector_type(8))) short bf16x8;
typedef __attribute__((ext_vector_type(4))) float f32x4;

__device__ __forceinline__ float bf2f(bfu u) {
  return __uint_as_float(((unsigned int)u) << 16);
}
__device__ __forceinline__ bfu f2bf(float f) {
  unsigned int i = __float_as_uint(f);
  unsigned int r = i + 0x7fffu + ((i >> 16) & 1u);
  return (bfu)(r >> 16);
}
__device__ __forceinline__ float gelu_exact(float x) {
  return 0.5f * x * (1.0f + erff(x * 0.70710678118654752f));
}

// KPREP: bid 0..23 wqkvT [kg16][n384][8k]; bid 24 zero bnacc;
// bid 25..40 ap0 = w_p0^T [kg16][f256][8k]; bid 41..56 ap2 = w_p2^T
// [kg32][c128][8k]; bid 57..64 awout = w_out^T [kg16][c128][8k]
__global__ __launch_bounds__(256) void kprep(
    const float* __restrict__ wqkv, const float* __restrict__ wp0,
    const float* __restrict__ wp2, const float* __restrict__ wout,
    bfu* __restrict__ wqkvT, bfu* __restrict__ ap0, bfu* __restrict__ ap2,
    bfu* __restrict__ awout, float* __restrict__ bnacc) {
  int bid = blockIdx.x;
  int tid = threadIdx.x;
  if (bid < 24) {
    int task = bid * 256 + tid;  // kg*384 + n
    int kg = task / 384, n = task % 384;
    bfu tmp[8];
    #pragma unroll
    for (int j = 0; j < 8; ++j) tmp[j] = f2bf(wqkv[(kg * 8 + j) * 384 + n]);
    *(uint4*)&wqkvT[(size_t)kg * 3072 + n * 8] = *(const uint4*)tmp;
  } else if (bid == 24) {
    bnacc[tid] = 0.f;
    bnacc[256 + tid] = 0.f;
  } else if (bid < 41) {
    int task = (bid - 25) * 256 + tid;  // kg*256 + f
    int kg = task >> 8, f = task & 255;
    bfu tmp[8];
    #pragma unroll
    for (int j = 0; j < 8; ++j) tmp[j] = f2bf(wp0[(kg * 8 + j) * 256 + f]);
    *(uint4*)&ap0[((size_t)kg * 256 + f) * 8] = *(const uint4*)tmp;
  } else if (bid < 57) {
    int task = (bid - 41) * 256 + tid;  // kg*128 + c
    int kg = task >> 7, c = task & 127;
    bfu tmp[8];
    #pragma unroll
    for (int j = 0; j < 8; ++j) tmp[j] = f2bf(wp2[(kg * 8 + j) * 128 + c]);
    *(uint4*)&ap2[((size_t)kg * 128 + c) * 8] = *(const uint4*)tmp;
  } else {
    int task = (bid - 57) * 256 + tid;  // kg*128 + c
    int kg = task >> 7, c = task & 127;
    bfu tmp[8];
    #pragma unroll
    for (int j = 0; j < 8; ++j) tmp[j] = f2bf(wout[(kg * 8 + j) * 128 + c]);
    *(uint4*)&awout[((size_t)kg * 128 + c) * 8] = *(const uint4*)tmp;
  }
}

// K1: gather -> tok fp32 [reg][c][t]; aln bf16 blocked [reg][g=c/8][t][8c]
__global__ __launch_bounds__(256) void k1_gather(
    const float* __restrict__ x, const float* __restrict__ g,
    const float* __restrict__ bia, float* __restrict__ tok,
    bfu* __restrict__ aln) {
  int reg = blockIdx.x;
  int b = reg / NREGB, ij = reg % NREGB;
  int i = ij / NR, j = ij % NR;
  int t = threadIdx.x;
  int r = t >> 4, s = t & 15;
  int hh = i * STEP + r, ww = j * STEP + s;
  const float* xp = x + (size_t)b * DIMC * HW + (size_t)hh * WW_ + ww;
  float* tp = tok + (size_t)reg * DIMC * TT + t;
  float sum = 0.f, sq = 0.f;
  #pragma unroll 4
  for (int c = 0; c < DIMC; ++c) {
    float v = xp[(size_t)c * HW];
    tp[c * TT] = v;
    sum += v;
    sq = fmaf(v, v, sq);
  }
  float mu = sum * (1.0f / DIMC);
  float var = sq * (1.0f / DIMC) - mu * mu;
  float rstd = rsqrtf(var + 1e-5f);
  bfu* ap = aln + (size_t)reg * 32768 + t * 8;
  #pragma unroll
  for (int gidx = 0; gidx < 16; ++gidx) {
    bfu tmp[8];
    #pragma unroll
    for (int jj = 0; jj < 8; ++jj) {
      int c = gidx * 8 + jj;
      float vv = xp[(size_t)c * HW];  // L2-hot re-read
      tmp[jj] = f2bf((vv - mu) * rstd * g[c] + bia[c]);
    }
    *(uint4*)&ap[(size_t)gidx * 2048] = *(const uint4*)tmp;
  }
}

// K2: LDS-free register MFMA GEMM (qkv)
__global__ __launch_bounds__(256) void k2_qkv(
    const bfu* __restrict__ aln, const bfu* __restrict__ wqkvT,
    bfu* __restrict__ qkvt) {
  int reg = blockIdx.x;
  int mt = blockIdx.y;
  int tid = threadIdx.x;
  int wave = tid >> 6, lane = tid & 63;
  int quad = lane >> 4, n16 = lane & 15;
  const bfu* ab = aln + (size_t)reg * 32768 + (mt * 64 + n16) * 8;
  const bfu* bb = wqkvT + (wave * 96 + n16) * 8;
  f32x4 acc[4][6];
  #pragma unroll
  for (int m = 0; m < 4; ++m)
    #pragma unroll
    for (int nt = 0; nt < 6; ++nt) acc[m][nt] = (f32x4){0.f, 0.f, 0.f, 0.f};
  #pragma unroll
  for (int ph = 0; ph < 4; ++ph) {
    int gg = ph * 4 + quad;
    bf16x8 af[4];
    #pragma unroll
    for (int m = 0; m < 4; ++m)
      af[m] = *(const bf16x8*)&ab[(size_t)gg * 2048 + m * 128];
    bf16x8 bfr[6];
    #pragma unroll
    for (int nt = 0; nt < 6; ++nt)
      bfr[nt] = *(const bf16x8*)&bb[(size_t)gg * 3072 + nt * 128];
    #pragma unroll
    for (int m = 0; m < 4; ++m)
      #pragma unroll
      for (int nt = 0; nt < 6; ++nt)
        acc[m][nt] =
            __builtin_amdgcn_mfma_f32_16x16x32_bf16(af[m], bfr[nt], acc[m][nt], 0, 0, 0);
  }
  bfu* outp =
      qkvt + ((size_t)reg * 256 + mt * 64 + quad * 4) * 384 + wave * 96 + n16;
  #pragma unroll
  for (int m = 0; m < 4; ++m)
    #pragma unroll
    for (int nt = 0; nt < 6; ++nt)
      #pragma unroll
      for (int r = 0; r < 4; ++r)
        outp[(m * 16 + r) * 384 + nt * 16] = f2bf(acc[m][nt][r]);
}

// K3: MFMA attention, S^T formulation — no P LDS round-trip.
// S^T = K·Q^T (A=K, B=Q); softmax over tok = 64 regs + 2 shfl;
// O^T = V^T·P^T with P^T packed in registers; V^T staged LDS-permuted.
__global__ __launch_bounds__(256) void k3_attn(
    const bfu* __restrict__ qkvt, bfu* __restrict__ o) {
  int reg = blockIdx.x;
  int h = blockIdx.y;
  // vperm: [g(8)][quad(4)] blocks of 264 u16 (d(32) x j(8), +8 pad)
  __shared__ __align__(16) bfu vperm[8 * 4 * 264];  // 16896 B
  int tid = threadIdx.x;
  int wave = tid >> 6, lane = tid & 63;
  int quad = lane >> 4, n16 = lane & 15;
  const bfu* qb = qkvt + (size_t)reg * 256 * 384;
  {
    // token t -> (g, quad_t, j_t): tok = g*32 + (j>=4)*16 + quad*4 + (j&3)
    int t = tid;
    int g = t >> 5, o32 = t & 31;
    int qd = (o32 & 15) >> 2;
    int jt = (o32 < 16) ? (o32 & 3) : 4 + (o32 & 3);
    const bfu* vrow = qb + t * 384 + 256 + h * 32;
    bfu* dst = &vperm[(g * 4 + qd) * 264 + jt];
    #pragma unroll
    for (int dg = 0; dg < 8; ++dg) {
      ushort4 v4 = *(const ushort4*)(vrow + dg * 4);
      dst[(dg * 4 + 0) * 8] = v4.x;
      dst[(dg * 4 + 1) * 8] = v4.y;
      dst[(dg * 4 + 2) * 8] = v4.z;
      dst[(dg * 4 + 3) * 8] = v4.w;
    }
  }
  __syncthreads();
  const bfu* kptr = qb + n16 * 384 + 128 + h * 32 + quad * 8;
  const f32x4 zero = {0.f, 0.f, 0.f, 0.f};
  const float scale = 0.17677669529663687f;  // 1/sqrt(32)
  for (int mi = 0; mi < 4; ++mi) {
    int mt = wave * 4 + mi;
    // B-frag: Q[qrow = mt*16+n16][d = quad*8..]
    bf16x8 qf = *(const bf16x8*)(qb + (mt * 16 + n16) * 384 + h * 32 + quad * 8);
    f32x4 st[16];
    #pragma unroll
    for (int T = 0; T < 16; ++T) {
      bf16x8 kf = *(const bf16x8*)(kptr + T * 16 * 384);
      st[T] = __builtin_amdgcn_mfma_f32_16x16x32_bf16(kf, qf, zero, 0, 0, 0);
    }
    // softmax over tok (rows of S^T): regs + cross-quad shfl
    float m = st[0][0];
    #pragma unroll
    for (int T = 0; T < 16; ++T)
      #pragma unroll
      for (int r = 0; r < 4; ++r) m = fmaxf(m, st[T][r]);
    m = fmaxf(m, __shfl_xor(m, 16, 64));
    m = fmaxf(m, __shfl_xor(m, 32, 64));
    float l = 0.f;
    #pragma unroll
    for (int T = 0; T < 16; ++T)
      #pragma unroll
      for (int r = 0; r < 4; ++r) {
        float p = __expf((st[T][r] - m) * scale);
        st[T][r] = p;
        l += p;
      }
    l += __shfl_xor(l, 16, 64);
    l += __shfl_xor(l, 32, 64);
    float inv = 1.0f / l;
    // PV: O^T = V^T (LDS, permuted) x P^T (registers)
    f32x4 oa0 = zero, oa1 = zero;
    #pragma unroll
    for (int g = 0; g < 8; ++g) {
      bfu pk[8];
      #pragma unroll
      for (int r = 0; r < 4; ++r) {
        pk[r] = f2bf(st[2 * g][r]);
        pk[4 + r] = f2bf(st[2 * g + 1][r]);
      }
      bf16x8 pf = *(const bf16x8*)pk;
      bf16x8 va = *(const bf16x8*)&vperm[(g * 4 + quad) * 264 + n16 * 8];
      bf16x8 vb = *(const bf16x8*)&vperm[(g * 4 + quad) * 264 + (16 + n16) * 8];
      oa0 = __builtin_amdgcn_mfma_f32_16x16x32_bf16(va, pf, oa0, 0, 0, 0);
      oa1 = __builtin_amdgcn_mfma_f32_16x16x32_bf16(vb, pf, oa1, 0, 0, 0);
    }
    // O^T C-layout: lane holds token (mt*16+n16), dims quad*4+r and +16
    bfu* ob = o + ((size_t)reg * 256 + mt * 16 + n16) * 128 + h * 32 + quad * 4;
    ushort4 s0, s1;
    s0.x = f2bf(oa0[0] * inv);
    s0.y = f2bf(oa0[1] * inv);
    s0.z = f2bf(oa0[2] * inv);
    s0.w = f2bf(oa0[3] * inv);
    s1.x = f2bf(oa1[0] * inv);
    s1.y = f2bf(oa1[1] * inv);
    s1.z = f2bf(oa1[2] * inv);
    s1.w = f2bf(oa1[3] * inv);
    *(ushort4*)&ob[0] = s0;
    *(ushort4*)&ob[16] = s1;
  }
}

// K4: tok[c][t] += o @ w_out + b_out via MFMA. A = w_out^T (M=c),
// B = o rows (token-major is B-frag-native). LDS-free.
__global__ __launch_bounds__(256) void k4_outproj(
    const bfu* __restrict__ o, const bfu* __restrict__ awout,
    const float* __restrict__ bout, float* __restrict__ tok) {
  int reg = blockIdx.x;
  int tt = blockIdx.y;
  int tid = threadIdx.x;
  int wave = tid >> 6, lane = tid & 63;
  int quad = lane >> 4, n16 = lane & 15;
  int t = tt * 64 + wave * 16 + n16;
  const bfu* ob = o + ((size_t)reg * 256 + t) * 128;
  f32x4 acc[8];
  #pragma unroll
  for (int mt = 0; mt < 8; ++mt) acc[mt] = (f32x4){0.f, 0.f, 0.f, 0.f};
  #pragma unroll
  for (int kt = 0; kt < 4; ++kt) {
    bf16x8 bfrag = *(const bf16x8*)&ob[kt * 32 + quad * 8];
    const bfu* arow = awout + ((size_t)(kt * 4 + quad) * 128 + n16) * 8;
    #pragma unroll
    for (int mt = 0; mt < 8; ++mt) {
      bf16x8 afrag = *(const bf16x8*)&arow[mt * 128];
      acc[mt] = __builtin_amdgcn_mfma_f32_16x16x32_bf16(afrag, bfrag, acc[mt], 0, 0, 0);
    }
  }
  float* tokr = tok + (size_t)reg * DIMC * TT + t;
  #pragma unroll
  for (int mt = 0; mt < 8; ++mt) {
    #pragma unroll
    for (int r = 0; r < 4; ++r) {
      int c = mt * 16 + quad * 4 + r;
      tokr[c * TT] += acc[mt][r] + bout[c];
    }
  }
}

// K5: overlap merge -> xf fp32 + xln = LN2'd bf16 blocked [b][cg][p][8c]
__global__ __launch_bounds__(512) void k5_merge(
    const float* __restrict__ tok, const float* __restrict__ ln2g,
    const float* __restrict__ ln2b, float* __restrict__ xf,
    bfu* __restrict__ xln) {
  int hh = blockIdx.x, b = blockIdx.y;
  int tid = threadIdx.x;
  int w = tid & 127, q = tid >> 7;
  int ilo = (hh >= 2) ? (hh - 2) / 14 : 0;
  int ihi = hh / 14;
  if (ihi > 8) ihi = 8;
  int jlo = (w >= 2) ? (w - 2) / 14 : 0;
  int jhi = w / 14;
  if (jhi > 8) jhi = 8;
  float rcnt = 1.0f / (float)((ihi - ilo + 1) * (jhi - jlo + 1));
  size_t offs[4];
  int nij = 0;
  for (int i = ilo; i <= ihi; ++i)
    for (int j = jlo; j <= jhi; ++j) {
      int reg = b * NREGB + i * NR + j;
      int r = hh - i * STEP, s = w - j * STEP;
      offs[nij++] = (size_t)reg * DIMC * TT + r * 16 + s;
    }
  float* xp = xf + ((size_t)b * DIMC << 14) + hh * WW_ + w;
  float mm[32];
  float sum = 0.f, sq = 0.f;
  int c0 = q * 32;
  for (int cc = 0; cc < 32; ++cc) {
    int c = c0 + cc;
    float s = 0.f;
    for (int k = 0; k < nij; ++k) s += tok[offs[k] + c * TT];
    float m = s * rcnt;
    xp[(size_t)c << 14] = m;
    mm[cc] = m;
    sum += m;
    sq = fmaf(m, m, sq);
  }
  __shared__ float rs[512];
  __shared__ float rq[512];
  __shared__ float muS[128];
  __shared__ float rsdS[128];
  rs[tid] = sum;
  rq[tid] = sq;
  __syncthreads();
  if (tid < 128) {
    float s4 = rs[tid] + rs[tid + 128] + rs[tid + 256] + rs[tid + 384];
    float q4 = rq[tid] + rq[tid + 128] + rq[tid + 256] + rq[tid + 384];
    float mu = s4 * (1.0f / DIMC);
    float var = q4 * (1.0f / DIMC) - mu * mu;
    muS[tid] = mu;
    rsdS[tid] = rsqrtf(var + 1e-5f);
  }
  __syncthreads();
  float mu = muS[w], rstd = rsdS[w];
  int p = hh * WW_ + w;
  #pragma unroll
  for (int gl = 0; gl < 4; ++gl) {
    int gidx = q * 4 + gl;
    bfu tmp[8];
    #pragma unroll
    for (int j = 0; j < 8; ++j) {
      int c = gidx * 8 + j;
      tmp[j] = f2bf((mm[gl * 8 + j] - mu) * rstd * ln2g[c] + ln2b[c]);
    }
    *(uint4*)&xln[(((size_t)(b * 16 + gidx) << 14) + p) * 8] = *(const uint4*)tmp;
  }
}

// K6: ym[b][f][p] = xln @ w_p0 + b_p0 via MFMA
__global__ __launch_bounds__(256) void k6_p0(
    const bfu* __restrict__ xln, const bfu* __restrict__ ap0,
    const float* __restrict__ bp0, bfu* __restrict__ ym) {
  int b = blockIdx.y;
  int ptile = blockIdx.x * 64;
  int tid = threadIdx.x;
  int wv = tid >> 6, lane = tid & 63;
  int quad = lane >> 4, n16 = lane & 15;
  int p = ptile + wv * 16 + n16;
  f32x4 acc[16];
  #pragma unroll
  for (int mt = 0; mt < 16; ++mt) acc[mt] = (f32x4){0.f, 0.f, 0.f, 0.f};
  #pragma unroll
  for (int ph = 0; ph < 4; ++ph) {
    int gg = ph * 4 + quad;
    bf16x8 bfrag = *(const bf16x8*)&xln[(((size_t)(b * 16 + gg) << 14) + p) * 8];
    const bfu* arow = ap0 + ((size_t)gg * 256 + n16) * 8;
    #pragma unroll
    for (int mt = 0; mt < 16; ++mt) {
      bf16x8 afrag = *(const bf16x8*)&arow[mt * 128];
      acc[mt] = __builtin_amdgcn_mfma_f32_16x16x32_bf16(afrag, bfrag, acc[mt], 0, 0, 0);
    }
  }
  #pragma unroll
  for (int mt = 0; mt < 16; ++mt) {
    #pragma unroll
    for (int r = 0; r < 4; ++r) {
      int f = mt * 16 + quad * 4 + r;
      ym[((size_t)(b * HID + f) << 14) + p] = f2bf(acc[mt][r] + bp0[f]);
    }
  }
}

// K7: 5x5 depthwise conv, whole plane in LDS, fused BN partials
__global__ __launch_bounds__(256) void k7_conv(
    const bfu* __restrict__ ym, const float* __restrict__ dwk,
    bfu* __restrict__ ym2, float* __restrict__ bnacc) {
  int bf = blockIdx.x;
  int f = bf & (HID - 1);
  __shared__ bfu sp[128 * 134];
  const bfu* in = ym + ((size_t)bf << 14);
  int tid = threadIdx.x;
  for (int idx = tid; idx < 2048; idx += 256) {
    int r = idx >> 4, c8 = (idx & 15) << 3;
    ushort4 a = *(const ushort4*)&in[(r << 7) + c8];
    ushort4 b = *(const ushort4*)&in[(r << 7) + c8 + 4];
    bfu* d = &sp[r * 134 + c8];
    d[0] = a.x; d[1] = a.y; d[2] = a.z; d[3] = a.w;
    d[4] = b.x; d[5] = b.y; d[6] = b.z; d[7] = b.w;
  }
  float wk[25];
  #pragma unroll
  for (int i = 0; i < 25; ++i) wk[i] = dwk[f * 25 + i];
  __syncthreads();
  int row = tid >> 1, half = (tid & 1) << 6;
  float acc[64];
  #pragma unroll
  for (int i = 0; i < 64; ++i) acc[i] = 0.f;
  #pragma unroll
  for (int ky = 0; ky < 5; ++ky) {
    int y = row + ky - 2;
    if (y < 0 || y >= 128) continue;
    const bfu* rp = &sp[y * 134];
    float win[68];
    #pragma unroll
    for (int c = 0; c < 68; ++c) {
      int cc = half + c - 2;
      win[c] = (cc >= 0 && cc < 128) ? bf2f(rp[cc]) : 0.f;
    }
    #pragma unroll
    for (int kx = 0; kx < 5; ++kx) {
      float wv = wk[ky * 5 + kx];
      #pragma unroll
      for (int i = 0; i < 64; ++i) acc[i] = fmaf(win[i + kx], wv, acc[i]);
    }
  }
  float s = 0.f, sq = 0.f;
  #pragma unroll
  for (int i = 0; i < 64; ++i) {
    s += acc[i];
    sq = fmaf(acc[i], acc[i], sq);
  }
  bfu* op = ym2 + ((size_t)bf << 14) + (row << 7) + half;
  #pragma unroll
  for (int g8 = 0; g8 < 8; ++g8) {
    bfu tmp[8];
    #pragma unroll
    for (int i = 0; i < 8; ++i) tmp[i] = f2bf(acc[g8 * 8 + i]);
    *(uint4*)&op[g8 * 8] = *(const uint4*)tmp;
  }
  __syncthreads();
  float* red = (float*)sp;
  red[tid] = s;
  red[256 + tid] = sq;
  __syncthreads();
  for (int o = 128; o > 0; o >>= 1) {
    if (tid < o) {
      red[tid] += red[tid + o];
      red[256 + tid] += red[256 + tid + o];
    }
    __syncthreads();
  }
  if (tid == 0) {
    atomicAdd(&bnacc[f], red[0]);
    atomicAdd(&bnacc[HID + f], red[256]);
  }
}

// K8: finalize BN stats
__global__ __launch_bounds__(256) void k8_fin(
    const float* __restrict__ bnacc, float* __restrict__ bnm,
    float* __restrict__ bnr) {
  int f = threadIdx.x;
  float mu = bnacc[f] * (1.0f / 65536.f);
  float var = bnacc[HID + f] * (1.0f / 65536.f) - mu * mu;
  bnm[f] = mu;
  bnr[f] = rsqrtf(var + 1e-5f);
}

// K9: g2b = gelu(gelu(bn(ym2))) in blocked [b][fg][p][8f]
__global__ __launch_bounds__(256) void k9_act(
    const bfu* __restrict__ ym2, const float* __restrict__ bnm,
    const float* __restrict__ bnr, const float* __restrict__ g,
    const float* __restrict__ bia, bfu* __restrict__ g2b) {
  int idx = blockIdx.x * 256 + threadIdx.x;
  int p = idx & 16383;
  int fg = (idx >> 14) & 31;
  int b = idx >> 19;
  bfu tmp[8];
  #pragma unroll
  for (int i = 0; i < 8; ++i) {
    int f = fg * 8 + i;
    float v = bf2f(ym2[((size_t)(b * HID + f) << 14) + p]);
    v = (v - bnm[f]) * (bnr[f] * g[f]) + bia[f];
    tmp[i] = f2bf(gelu_exact(gelu_exact(v)));
  }
  *(uint4*)&g2b[(((size_t)(b * 32 + fg) << 14) + p) * 8] = *(const uint4*)tmp;
}

// K10: out = g2 @ w_p2 + b_p2 + xf via MFMA
__global__ __launch_bounds__(256) void k10_p2(
    const bfu* __restrict__ g2b, const bfu* __restrict__ ap2,
    const float* __restrict__ bp2, const float* __restrict__ xf,
    float* __restrict__ outp) {
  int b = blockIdx.y;
  int ptile = blockIdx.x * 64;
  int tid = threadIdx.x;
  int wv = tid >> 6, lane = tid & 63;
  int quad = lane >> 4, n16 = lane & 15;
  int p = ptile + wv * 16 + n16;
  f32x4 acc[8];
  #pragma unroll
  for (int mt = 0; mt < 8; ++mt) acc[mt] = (f32x4){0.f, 0.f, 0.f, 0.f};
  #pragma unroll
  for (int ph = 0; ph < 8; ++ph) {
    int gg = ph * 4 + quad;
    bf16x8 bfrag = *(const bf16x8*)&g2b[(((size_t)(b * 32 + gg) << 14) + p) * 8];
    const bfu* arow = ap2 + ((size_t)gg * 128 + n16) * 8;
    #pragma unroll
    for (int mt = 0; mt < 8; ++mt) {
      bf16x8 afrag = *(const bf16x8*)&arow[mt * 128];
      acc[mt] = __builtin_amdgcn_mfma_f32_16x16x32_bf16(afrag, bfrag, acc[mt], 0, 0, 0);
    }
  }
  #pragma unroll
  for (int mt = 0; mt < 8; ++mt) {
    #pragma unroll
    for (int r = 0; r < 4; ++r) {
      int c = mt * 16 + quad * 4 + r;
      size_t off = ((size_t)(b * DIMC + c) << 14) + p;
      outp[off] = acc[mt][r] + bp2[c] + xf[off];
    }
  }
}

extern "C" void kernel_launch(void* const* d_in, const int* in_sizes, int n_in,
                              void* d_out, int out_size, void* d_ws,
                              size_t ws_size, hipStream_t stream) {
  const float* x = (const float*)d_in[0];
  const float* ln1_g = (const float*)d_in[1];
  const float* ln1_b = (const float*)d_in[2];
  const float* w_qkv = (const float*)d_in[3];
  const float* w_out = (const float*)d_in[4];
  const float* b_out = (const float*)d_in[5];
  const float* ln2_g = (const float*)d_in[6];
  const float* ln2_b = (const float*)d_in[7];
  const float* w_p0 = (const float*)d_in[8];
  const float* b_p0 = (const float*)d_in[9];
  const float* dw_k = (const float*)d_in[10];
  const float* bn_g = (const float*)d_in[11];
  const float* bn_b = (const float*)d_in[12];
  const float* w_p2 = (const float*)d_in[13];
  const float* b_p2 = (const float*)d_in[14];
  float* outp = (float*)d_out;

  char* ws = (char*)d_ws;
  size_t off = 0;
  auto alloc = [&](size_t bytes) {
    void* p = ws + off;
    off += (bytes + 1023) & ~(size_t)1023;
    return p;
  };
  float* tok = (float*)alloc((size_t)NREG * DIMC * TT * 4);
  bfu* qkvt = (bfu*)alloc((size_t)NREG * 384 * TT * 2);
  float* xf = (float*)alloc((size_t)BB * DIMC * HW * 4);
  bfu* xln = (bfu*)alloc((size_t)BB * DIMC * HW * 2);
  bfu* ym = (bfu*)alloc((size_t)BB * HID * HW * 2);
  bfu* ym2 = (bfu*)alloc((size_t)BB * HID * HW * 2);
  float* bnacc = (float*)alloc(2 * HID * 4);
  float* bnm = (float*)alloc(HID * 4);
  float* bnr = (float*)alloc(HID * 4);
  bfu* wqkvT = (bfu*)alloc(16 * 3072 * 2);
  bfu* ap0 = (bfu*)alloc(16 * 256 * 8 * 2);
  bfu* ap2 = (bfu*)alloc(32 * 128 * 8 * 2);
  bfu* awout = (bfu*)alloc(16 * 128 * 8 * 2);
  // overlays (lifetimes disjoint)
  bfu* o = ym;     // used k3->k4; ym written first in k6
  bfu* aln = ym2;  // used k1->k2; ym2 written first in k7
  bfu* g2b = ym;   // used k9->k10; ym consumed by k7 before k9

  kprep<<<65, 256, 0, stream>>>(w_qkv, w_p0, w_p2, w_out, wqkvT, ap0, ap2,
                                awout, bnacc);
  k1_gather<<<NREG, 256, 0, stream>>>(x, ln1_g, ln1_b, tok, aln);
  k2_qkv<<<dim3(NREG, 4), 256, 0, stream>>>(aln, wqkvT, qkvt);
  k3_attn<<<dim3(NREG, NHEADS), 256, 0, stream>>>(qkvt, o);
  k4_outproj<<<dim3(NREG, 4), 256, 0, stream>>>(o, awout, b_out, tok);
  k5_merge<<<dim3(HH_, BB), 512, 0, stream>>>(tok, ln2_g, ln2_b, xf, xln);
  k6_p0<<<dim3(256, BB), 256, 0, stream>>>(xln, ap0, b_p0, ym);
  k7_conv<<<BB * HID, 256, 0, stream>>>(ym, dw_k, ym2, bnacc);
  k8_fin<<<1, 256, 0, stream>>>(bnacc, bnm, bnr);
  k9_act<<<8192, 256, 0, stream>>>(ym2, bnm, bnr, bn_g, bn_b, g2b);
  k10_p2<<<dim3(256, BB), 256, 0, stream>>>(g2b, ap2, b_p2, xf, outp);
}

// Round 8
// 416.461 us; speedup vs baseline: 1.4716x; 1.0261x over previous
//
#include <hip/hip_runtime.h>

#define DIMC 128
#define NHEADS 4
#define HD 32
#define HID 256
#define BB 4
#define HH_ 128
#define WW_ 128
#define HW 16384
#define RS 16
#define STEP 14
#define NR 9
#define NREGB 81
#define NREG 324
#define TT 256

typedef unsigned short bfu;  // bf16 bits
typedef __attribute__((ext_vector_type(8))) short bf16x8;
typedef __attribute__((ext_vector_type(4))) float f32x4;

__device__ __forceinline__ float bf2f(bfu u) {
  return __uint_as_float(((unsigned int)u) << 16);
}
__device__ __forceinline__ bfu f2bf(float f) {
  unsigned int i = __float_as_uint(f);
  unsigned int r = i + 0x7fffu + ((i >> 16) & 1u);
  return (bfu)(r >> 16);
}
__device__ __forceinline__ float gelu_exact(float x) {
  return 0.5f * x * (1.0f + erff(x * 0.70710678118654752f));
}

// KPREP: bid 0..23 wqkvT [kg16][n384][8k]; bid 24 zero bnacc;
// bid 25..40 ap0; bid 41..56 ap2; bid 57..64 awout
__global__ __launch_bounds__(256) void kprep(
    const float* __restrict__ wqkv, const float* __restrict__ wp0,
    const float* __restrict__ wp2, const float* __restrict__ wout,
    bfu* __restrict__ wqkvT, bfu* __restrict__ ap0, bfu* __restrict__ ap2,
    bfu* __restrict__ awout, float* __restrict__ bnacc) {
  int bid = blockIdx.x;
  int tid = threadIdx.x;
  if (bid < 24) {
    int task = bid * 256 + tid;  // kg*384 + n
    int kg = task / 384, n = task % 384;
    bfu tmp[8];
    #pragma unroll
    for (int j = 0; j < 8; ++j) tmp[j] = f2bf(wqkv[(kg * 8 + j) * 384 + n]);
    *(uint4*)&wqkvT[(size_t)kg * 3072 + n * 8] = *(const uint4*)tmp;
  } else if (bid == 24) {
    bnacc[tid] = 0.f;
    bnacc[256 + tid] = 0.f;
  } else if (bid < 41) {
    int task = (bid - 25) * 256 + tid;  // kg*256 + f
    int kg = task >> 8, f = task & 255;
    bfu tmp[8];
    #pragma unroll
    for (int j = 0; j < 8; ++j) tmp[j] = f2bf(wp0[(kg * 8 + j) * 256 + f]);
    *(uint4*)&ap0[((size_t)kg * 256 + f) * 8] = *(const uint4*)tmp;
  } else if (bid < 57) {
    int task = (bid - 41) * 256 + tid;  // kg*128 + c
    int kg = task >> 7, c = task & 127;
    bfu tmp[8];
    #pragma unroll
    for (int j = 0; j < 8; ++j) tmp[j] = f2bf(wp2[(kg * 8 + j) * 128 + c]);
    *(uint4*)&ap2[((size_t)kg * 128 + c) * 8] = *(const uint4*)tmp;
  } else {
    int task = (bid - 57) * 256 + tid;  // kg*128 + c
    int kg = task >> 7, c = task & 127;
    bfu tmp[8];
    #pragma unroll
    for (int j = 0; j < 8; ++j) tmp[j] = f2bf(wout[(kg * 8 + j) * 128 + c]);
    *(uint4*)&awout[((size_t)kg * 128 + c) * 8] = *(const uint4*)tmp;
  }
}

// K1: gather -> tok bf16 [reg][c][t]; aln bf16 blocked [reg][g=c/8][t][8c]
__global__ __launch_bounds__(256) void k1_gather(
    const float* __restrict__ x, const float* __restrict__ g,
    const float* __restrict__ bia, bfu* __restrict__ tok,
    bfu* __restrict__ aln) {
  int reg = blockIdx.x;
  int b = reg / NREGB, ij = reg % NREGB;
  int i = ij / NR, j = ij % NR;
  int t = threadIdx.x;
  int r = t >> 4, s = t & 15;
  int hh = i * STEP + r, ww = j * STEP + s;
  const float* xp = x + (size_t)b * DIMC * HW + (size_t)hh * WW_ + ww;
  bfu* tp = tok + (size_t)reg * DIMC * TT + t;
  float sum = 0.f, sq = 0.f;
  #pragma unroll 4
  for (int c = 0; c < DIMC; ++c) {
    float v = xp[(size_t)c * HW];
    tp[c * TT] = f2bf(v);
    sum += v;
    sq = fmaf(v, v, sq);
  }
  float mu = sum * (1.0f / DIMC);
  float var = sq * (1.0f / DIMC) - mu * mu;
  float rstd = rsqrtf(var + 1e-5f);
  bfu* ap = aln + (size_t)reg * 32768 + t * 8;
  #pragma unroll
  for (int gidx = 0; gidx < 16; ++gidx) {
    bfu tmp[8];
    #pragma unroll
    for (int jj = 0; jj < 8; ++jj) {
      int c = gidx * 8 + jj;
      float vv = xp[(size_t)c * HW];  // L2-hot re-read
      tmp[jj] = f2bf((vv - mu) * rstd * g[c] + bia[c]);
    }
    *(uint4*)&ap[(size_t)gidx * 2048] = *(const uint4*)tmp;
  }
}

// K2: LDS-free register MFMA GEMM (qkv)
__global__ __launch_bounds__(256) void k2_qkv(
    const bfu* __restrict__ aln, const bfu* __restrict__ wqkvT,
    bfu* __restrict__ qkvt) {
  int reg = blockIdx.x;
  int mt = blockIdx.y;
  int tid = threadIdx.x;
  int wave = tid >> 6, lane = tid & 63;
  int quad = lane >> 4, n16 = lane & 15;
  const bfu* ab = aln + (size_t)reg * 32768 + (mt * 64 + n16) * 8;
  const bfu* bb = wqkvT + (wave * 96 + n16) * 8;
  f32x4 acc[4][6];
  #pragma unroll
  for (int m = 0; m < 4; ++m)
    #pragma unroll
    for (int nt = 0; nt < 6; ++nt) acc[m][nt] = (f32x4){0.f, 0.f, 0.f, 0.f};
  #pragma unroll
  for (int ph = 0; ph < 4; ++ph) {
    int gg = ph * 4 + quad;
    bf16x8 af[4];
    #pragma unroll
    for (int m = 0; m < 4; ++m)
      af[m] = *(const bf16x8*)&ab[(size_t)gg * 2048 + m * 128];
    bf16x8 bfr[6];
    #pragma unroll
    for (int nt = 0; nt < 6; ++nt)
      bfr[nt] = *(const bf16x8*)&bb[(size_t)gg * 3072 + nt * 128];
    #pragma unroll
    for (int m = 0; m < 4; ++m)
      #pragma unroll
      for (int nt = 0; nt < 6; ++nt)
        acc[m][nt] =
            __builtin_amdgcn_mfma_f32_16x16x32_bf16(af[m], bfr[nt], acc[m][nt], 0, 0, 0);
  }
  bfu* outp =
      qkvt + ((size_t)reg * 256 + mt * 64 + quad * 4) * 384 + wave * 96 + n16;
  #pragma unroll
  for (int m = 0; m < 4; ++m)
    #pragma unroll
    for (int nt = 0; nt < 6; ++nt)
      #pragma unroll
      for (int r = 0; r < 4; ++r)
        outp[(m * 16 + r) * 384 + nt * 16] = f2bf(acc[m][nt][r]);
}

// K3: MFMA attention, S^T formulation; K AND V staged in LDS.
__global__ __launch_bounds__(256) void k3_attn(
    const bfu* __restrict__ qkvt, bfu* __restrict__ o) {
  int reg = blockIdx.x;
  int h = blockIdx.y;
  __shared__ __align__(16) bfu sK[256 * 40];        // [tok][d32 +8pad] 20.5KB
  __shared__ __align__(16) bfu vperm[8 * 4 * 264];  // 16.9KB
  int tid = threadIdx.x;
  int wave = tid >> 6, lane = tid & 63;
  int quad = lane >> 4, n16 = lane & 15;
  const bfu* qb = qkvt + (size_t)reg * 256 * 384;
  {
    int t = tid;
    // stage K: plain [tok][d] rows, b128 writes
    const bfu* krow = qb + t * 384 + 128 + h * 32;
    #pragma unroll
    for (int dg = 0; dg < 4; ++dg)
      *(uint4*)&sK[t * 40 + dg * 8] = *(const uint4*)(krow + dg * 8);
    // stage V permuted: tok t -> (g, quad_t, j_t)
    int g = t >> 5, o32 = t & 31;
    int qd = (o32 & 15) >> 2;
    int jt = (o32 < 16) ? (o32 & 3) : 4 + (o32 & 3);
    const bfu* vrow = qb + t * 384 + 256 + h * 32;
    bfu* dst = &vperm[(g * 4 + qd) * 264 + jt];
    #pragma unroll
    for (int dg = 0; dg < 8; ++dg) {
      ushort4 v4 = *(const ushort4*)(vrow + dg * 4);
      dst[(dg * 4 + 0) * 8] = v4.x;
      dst[(dg * 4 + 1) * 8] = v4.y;
      dst[(dg * 4 + 2) * 8] = v4.z;
      dst[(dg * 4 + 3) * 8] = v4.w;
    }
  }
  __syncthreads();
  const f32x4 zero = {0.f, 0.f, 0.f, 0.f};
  const float scale = 0.17677669529663687f;  // 1/sqrt(32)
  for (int mi = 0; mi < 4; ++mi) {
    int mt = wave * 4 + mi;
    bf16x8 qf = *(const bf16x8*)(qb + (mt * 16 + n16) * 384 + h * 32 + quad * 8);
    f32x4 st[16];
    #pragma unroll
    for (int T = 0; T < 16; ++T) {
      bf16x8 kf = *(const bf16x8*)&sK[(T * 16 + n16) * 40 + quad * 8];
      st[T] = __builtin_amdgcn_mfma_f32_16x16x32_bf16(kf, qf, zero, 0, 0, 0);
    }
    float m = st[0][0];
    #pragma unroll
    for (int T = 0; T < 16; ++T)
      #pragma unroll
      for (int r = 0; r < 4; ++r) m = fmaxf(m, st[T][r]);
    m = fmaxf(m, __shfl_xor(m, 16, 64));
    m = fmaxf(m, __shfl_xor(m, 32, 64));
    float l = 0.f;
    #pragma unroll
    for (int T = 0; T < 16; ++T)
      #pragma unroll
      for (int r = 0; r < 4; ++r) {
        float p = __expf((st[T][r] - m) * scale);
        st[T][r] = p;
        l += p;
      }
    l += __shfl_xor(l, 16, 64);
    l += __shfl_xor(l, 32, 64);
    float inv = 1.0f / l;
    f32x4 oa0 = zero, oa1 = zero;
    #pragma unroll
    for (int g = 0; g < 8; ++g) {
      bfu pk[8];
      #pragma unroll
      for (int r = 0; r < 4; ++r) {
        pk[r] = f2bf(st[2 * g][r]);
        pk[4 + r] = f2bf(st[2 * g + 1][r]);
      }
      bf16x8 pf = *(const bf16x8*)pk;
      bf16x8 va = *(const bf16x8*)&vperm[(g * 4 + quad) * 264 + n16 * 8];
      bf16x8 vb = *(const bf16x8*)&vperm[(g * 4 + quad) * 264 + (16 + n16) * 8];
      oa0 = __builtin_amdgcn_mfma_f32_16x16x32_bf16(va, pf, oa0, 0, 0, 0);
      oa1 = __builtin_amdgcn_mfma_f32_16x16x32_bf16(vb, pf, oa1, 0, 0, 0);
    }
    bfu* ob = o + ((size_t)reg * 256 + mt * 16 + n16) * 128 + h * 32 + quad * 4;
    ushort4 s0, s1;
    s0.x = f2bf(oa0[0] * inv);
    s0.y = f2bf(oa0[1] * inv);
    s0.z = f2bf(oa0[2] * inv);
    s0.w = f2bf(oa0[3] * inv);
    s1.x = f2bf(oa1[0] * inv);
    s1.y = f2bf(oa1[1] * inv);
    s1.z = f2bf(oa1[2] * inv);
    s1.w = f2bf(oa1[3] * inv);
    *(ushort4*)&ob[0] = s0;
    *(ushort4*)&ob[16] = s1;
  }
}

// K4: tok[c][t] (bf16) += o @ w_out + b_out via MFMA, LDS-free
__global__ __launch_bounds__(256) void k4_outproj(
    const bfu* __restrict__ o, const bfu* __restrict__ awout,
    const float* __restrict__ bout, bfu* __restrict__ tok) {
  int reg = blockIdx.x;
  int tt = blockIdx.y;
  int tid = threadIdx.x;
  int wave = tid >> 6, lane = tid & 63;
  int quad = lane >> 4, n16 = lane & 15;
  int t = tt * 64 + wave * 16 + n16;
  const bfu* ob = o + ((size_t)reg * 256 + t) * 128;
  f32x4 acc[8];
  #pragma unroll
  for (int mt = 0; mt < 8; ++mt) acc[mt] = (f32x4){0.f, 0.f, 0.f, 0.f};
  #pragma unroll
  for (int kt = 0; kt < 4; ++kt) {
    bf16x8 bfrag = *(const bf16x8*)&ob[kt * 32 + quad * 8];
    const bfu* arow = awout + ((size_t)(kt * 4 + quad) * 128 + n16) * 8;
    #pragma unroll
    for (int mt = 0; mt < 8; ++mt) {
      bf16x8 afrag = *(const bf16x8*)&arow[mt * 128];
      acc[mt] = __builtin_amdgcn_mfma_f32_16x16x32_bf16(afrag, bfrag, acc[mt], 0, 0, 0);
    }
  }
  bfu* tokr = tok + (size_t)reg * DIMC * TT + t;
  #pragma unroll
  for (int mt = 0; mt < 8; ++mt) {
    #pragma unroll
    for (int r = 0; r < 4; ++r) {
      int c = mt * 16 + quad * 4 + r;
      float val = bf2f(tokr[c * TT]) + acc[mt][r] + bout[c];
      tokr[c * TT] = f2bf(val);
    }
  }
}

// K5: overlap merge (bf16 tok) -> xf fp32 + xln bf16 blocked [b][cg][p][8c]
__global__ __launch_bounds__(512) void k5_merge(
    const bfu* __restrict__ tok, const float* __restrict__ ln2g,
    const float* __restrict__ ln2b, float* __restrict__ xf,
    bfu* __restrict__ xln) {
  int hh = blockIdx.x, b = blockIdx.y;
  int tid = threadIdx.x;
  int w = tid & 127, q = tid >> 7;
  int ilo = (hh >= 2) ? (hh - 2) / 14 : 0;
  int ihi = hh / 14;
  if (ihi > 8) ihi = 8;
  int jlo = (w >= 2) ? (w - 2) / 14 : 0;
  int jhi = w / 14;
  if (jhi > 8) jhi = 8;
  float rcnt = 1.0f / (float)((ihi - ilo + 1) * (jhi - jlo + 1));
  size_t offs[4];
  int nij = 0;
  for (int i = ilo; i <= ihi; ++i)
    for (int j = jlo; j <= jhi; ++j) {
      int reg = b * NREGB + i * NR + j;
      int r = hh - i * STEP, s = w - j * STEP;
      offs[nij++] = (size_t)reg * DIMC * TT + r * 16 + s;
    }
  float* xp = xf + ((size_t)b * DIMC << 14) + hh * WW_ + w;
  float mm[32];
  float sum = 0.f, sq = 0.f;
  int c0 = q * 32;
  for (int cc = 0; cc < 32; ++cc) {
    int c = c0 + cc;
    float s = 0.f;
    for (int k = 0; k < nij; ++k) s += bf2f(tok[offs[k] + c * TT]);
    float m = s * rcnt;
    xp[(size_t)c << 14] = m;
    mm[cc] = m;
    sum += m;
    sq = fmaf(m, m, sq);
  }
  __shared__ float rs[512];
  __shared__ float rq[512];
  __shared__ float muS[128];
  __shared__ float rsdS[128];
  rs[tid] = sum;
  rq[tid] = sq;
  __syncthreads();
  if (tid < 128) {
    float s4 = rs[tid] + rs[tid + 128] + rs[tid + 256] + rs[tid + 384];
    float q4 = rq[tid] + rq[tid + 128] + rq[tid + 256] + rq[tid + 384];
    float mu = s4 * (1.0f / DIMC);
    float var = q4 * (1.0f / DIMC) - mu * mu;
    muS[tid] = mu;
    rsdS[tid] = rsqrtf(var + 1e-5f);
  }
  __syncthreads();
  float mu = muS[w], rstd = rsdS[w];
  int p = hh * WW_ + w;
  #pragma unroll
  for (int gl = 0; gl < 4; ++gl) {
    int gidx = q * 4 + gl;
    bfu tmp[8];
    #pragma unroll
    for (int j = 0; j < 8; ++j) {
      int c = gidx * 8 + j;
      tmp[j] = f2bf((mm[gl * 8 + j] - mu) * rstd * ln2g[c] + ln2b[c]);
    }
    *(uint4*)&xln[(((size_t)(b * 16 + gidx) << 14) + p) * 8] = *(const uint4*)tmp;
  }
}

// K6: ym[b][f][p] = xln @ w_p0 + b_p0 via MFMA
__global__ __launch_bounds__(256) void k6_p0(
    const bfu* __restrict__ xln, const bfu* __restrict__ ap0,
    const float* __restrict__ bp0, bfu* __restrict__ ym) {
  int b = blockIdx.y;
  int ptile = blockIdx.x * 64;
  int tid = threadIdx.x;
  int wv = tid >> 6, lane = tid & 63;
  int quad = lane >> 4, n16 = lane & 15;
  int p = ptile + wv * 16 + n16;
  f32x4 acc[16];
  #pragma unroll
  for (int mt = 0; mt < 16; ++mt) acc[mt] = (f32x4){0.f, 0.f, 0.f, 0.f};
  #pragma unroll
  for (int ph = 0; ph < 4; ++ph) {
    int gg = ph * 4 + quad;
    bf16x8 bfrag = *(const bf16x8*)&xln[(((size_t)(b * 16 + gg) << 14) + p) * 8];
    const bfu* arow = ap0 + ((size_t)gg * 256 + n16) * 8;
    #pragma unroll
    for (int mt = 0; mt < 16; ++mt) {
      bf16x8 afrag = *(const bf16x8*)&arow[mt * 128];
      acc[mt] = __builtin_amdgcn_mfma_f32_16x16x32_bf16(afrag, bfrag, acc[mt], 0, 0, 0);
    }
  }
  #pragma unroll
  for (int mt = 0; mt < 16; ++mt) {
    #pragma unroll
    for (int r = 0; r < 4; ++r) {
      int f = mt * 16 + quad * 4 + r;
      ym[((size_t)(b * HID + f) << 14) + p] = f2bf(acc[mt][r] + bp0[f]);
    }
  }
}

// K7: 5x5 depthwise conv, whole plane in LDS, fused BN partials
__global__ __launch_bounds__(256) void k7_conv(
    const bfu* __restrict__ ym, const float* __restrict__ dwk,
    bfu* __restrict__ ym2, float* __restrict__ bnacc) {
  int bf = blockIdx.x;
  int f = bf & (HID - 1);
  __shared__ bfu sp[128 * 134];
  const bfu* in = ym + ((size_t)bf << 14);
  int tid = threadIdx.x;
  for (int idx = tid; idx < 2048; idx += 256) {
    int r = idx >> 4, c8 = (idx & 15) << 3;
    ushort4 a = *(const ushort4*)&in[(r << 7) + c8];
    ushort4 b = *(const ushort4*)&in[(r << 7) + c8 + 4];
    bfu* d = &sp[r * 134 + c8];
    d[0] = a.x; d[1] = a.y; d[2] = a.z; d[3] = a.w;
    d[4] = b.x; d[5] = b.y; d[6] = b.z; d[7] = b.w;
  }
  float wk[25];
  #pragma unroll
  for (int i = 0; i < 25; ++i) wk[i] = dwk[f * 25 + i];
  __syncthreads();
  int row = tid >> 1, half = (tid & 1) << 6;
  float acc[64];
  #pragma unroll
  for (int i = 0; i < 64; ++i) acc[i] = 0.f;
  #pragma unroll
  for (int ky = 0; ky < 5; ++ky) {
    int y = row + ky - 2;
    if (y < 0 || y >= 128) continue;
    const bfu* rp = &sp[y * 134];
    float win[68];
    #pragma unroll
    for (int c = 0; c < 68; ++c) {
      int cc = half + c - 2;
      win[c] = (cc >= 0 && cc < 128) ? bf2f(rp[cc]) : 0.f;
    }
    #pragma unroll
    for (int kx = 0; kx < 5; ++kx) {
      float wv = wk[ky * 5 + kx];
      #pragma unroll
      for (int i = 0; i < 64; ++i) acc[i] = fmaf(win[i + kx], wv, acc[i]);
    }
  }
  float s = 0.f, sq = 0.f;
  #pragma unroll
  for (int i = 0; i < 64; ++i) {
    s += acc[i];
    sq = fmaf(acc[i], acc[i], sq);
  }
  bfu* op = ym2 + ((size_t)bf << 14) + (row << 7) + half;
  #pragma unroll
  for (int g8 = 0; g8 < 8; ++g8) {
    bfu tmp[8];
    #pragma unroll
    for (int i = 0; i < 8; ++i) tmp[i] = f2bf(acc[g8 * 8 + i]);
    *(uint4*)&op[g8 * 8] = *(const uint4*)tmp;
  }
  __syncthreads();
  float* red = (float*)sp;
  red[tid] = s;
  red[256 + tid] = sq;
  __syncthreads();
  for (int o = 128; o > 0; o >>= 1) {
    if (tid < o) {
      red[tid] += red[tid + o];
      red[256 + tid] += red[256 + tid + o];
    }
    __syncthreads();
  }
  if (tid == 0) {
    atomicAdd(&bnacc[f], red[0]);
    atomicAdd(&bnacc[HID + f], red[256]);
  }
}

// K8: finalize BN stats
__global__ __launch_bounds__(256) void k8_fin(
    const float* __restrict__ bnacc, float* __restrict__ bnm,
    float* __restrict__ bnr) {
  int f = threadIdx.x;
  float mu = bnacc[f] * (1.0f / 65536.f);
  float var = bnacc[HID + f] * (1.0f / 65536.f) - mu * mu;
  bnm[f] = mu;
  bnr[f] = rsqrtf(var + 1e-5f);
}

// K9: g2b = gelu(gelu(bn(ym2))) in blocked [b][fg][p][8f]
__global__ __launch_bounds__(256) void k9_act(
    const bfu* __restrict__ ym2, const float* __restrict__ bnm,
    const float* __restrict__ bnr, const float* __restrict__ g,
    const float* __restrict__ bia, bfu* __restrict__ g2b) {
  int idx = blockIdx.x * 256 + threadIdx.x;
  int p = idx & 16383;
  int fg = (idx >> 14) & 31;
  int b = idx >> 19;
  bfu tmp[8];
  #pragma unroll
  for (int i = 0; i < 8; ++i) {
    int f = fg * 8 + i;
    float v = bf2f(ym2[((size_t)(b * HID + f) << 14) + p]);
    v = (v - bnm[f]) * (bnr[f] * g[f]) + bia[f];
    tmp[i] = f2bf(gelu_exact(gelu_exact(v)));
  }
  *(uint4*)&g2b[(((size_t)(b * 32 + fg) << 14) + p) * 8] = *(const uint4*)tmp;
}

// K10: out = g2 @ w_p2 + b_p2 + xf via MFMA
__global__ __launch_bounds__(256) void k10_p2(
    const bfu* __restrict__ g2b, const bfu* __restrict__ ap2,
    const float* __restrict__ bp2, const float* __restrict__ xf,
    float* __restrict__ outp) {
  int b = blockIdx.y;
  int ptile = blockIdx.x * 64;
  int tid = threadIdx.x;
  int wv = tid >> 6, lane = tid & 63;
  int quad = lane >> 4, n16 = lane & 15;
  int p = ptile + wv * 16 + n16;
  f32x4 acc[8];
  #pragma unroll
  for (int mt = 0; mt < 8; ++mt) acc[mt] = (f32x4){0.f, 0.f, 0.f, 0.f};
  #pragma unroll
  for (int ph = 0; ph < 8; ++ph) {
    int gg = ph * 4 + quad;
    bf16x8 bfrag = *(const bf16x8*)&g2b[(((size_t)(b * 32 + gg) << 14) + p) * 8];
    const bfu* arow = ap2 + ((size_t)gg * 128 + n16) * 8;
    #pragma unroll
    for (int mt = 0; mt < 8; ++mt) {
      bf16x8 afrag = *(const bf16x8*)&arow[mt * 128];
      acc[mt] = __builtin_amdgcn_mfma_f32_16x16x32_bf16(afrag, bfrag, acc[mt], 0, 0, 0);
    }
  }
  #pragma unroll
  for (int mt = 0; mt < 8; ++mt) {
    #pragma unroll
    for (int r = 0; r < 4; ++r) {
      int c = mt * 16 + quad * 4 + r;
      size_t off = ((size_t)(b * DIMC + c) << 14) + p;
      outp[off] = acc[mt][r] + bp2[c] + xf[off];
    }
  }
}

extern "C" void kernel_launch(void* const* d_in, const int* in_sizes, int n_in,
                              void* d_out, int out_size, void* d_ws,
                              size_t ws_size, hipStream_t stream) {
  const float* x = (const float*)d_in[0];
  const float* ln1_g = (const float*)d_in[1];
  const float* ln1_b = (const float*)d_in[2];
  const float* w_qkv = (const float*)d_in[3];
  const float* w_out = (const float*)d_in[4];
  const float* b_out = (const float*)d_in[5];
  const float* ln2_g = (const float*)d_in[6];
  const float* ln2_b = (const float*)d_in[7];
  const float* w_p0 = (const float*)d_in[8];
  const float* b_p0 = (const float*)d_in[9];
  const float* dw_k = (const float*)d_in[10];
  const float* bn_g = (const float*)d_in[11];
  const float* bn_b = (const float*)d_in[12];
  const float* w_p2 = (const float*)d_in[13];
  const float* b_p2 = (const float*)d_in[14];
  float* outp = (float*)d_out;

  char* ws = (char*)d_ws;
  size_t off = 0;
  auto alloc = [&](size_t bytes) {
    void* p = ws + off;
    off += (bytes + 1023) & ~(size_t)1023;
    return p;
  };
  bfu* tok = (bfu*)alloc((size_t)NREG * DIMC * TT * 2);
  bfu* qkvt = (bfu*)alloc((size_t)NREG * 384 * TT * 2);
  float* xf = (float*)alloc((size_t)BB * DIMC * HW * 4);
  bfu* xln = (bfu*)alloc((size_t)BB * DIMC * HW * 2);
  bfu* ym = (bfu*)alloc((size_t)BB * HID * HW * 2);
  bfu* ym2 = (bfu*)alloc((size_t)BB * HID * HW * 2);
  float* bnacc = (float*)alloc(2 * HID * 4);
  float* bnm = (float*)alloc(HID * 4);
  float* bnr = (float*)alloc(HID * 4);
  bfu* wqkvT = (bfu*)alloc(16 * 3072 * 2);
  bfu* ap0 = (bfu*)alloc(16 * 256 * 8 * 2);
  bfu* ap2 = (bfu*)alloc(32 * 128 * 8 * 2);
  bfu* awout = (bfu*)alloc(16 * 128 * 8 * 2);
  // overlays (lifetimes disjoint)
  bfu* o = ym;     // used k3->k4; ym written first in k6
  bfu* aln = ym2;  // used k1->k2; ym2 written first in k7
  bfu* g2b = ym;   // used k9->k10; ym consumed by k7 before k9

  kprep<<<65, 256, 0, stream>>>(w_qkv, w_p0, w_p2, w_out, wqkvT, ap0, ap2,
                                awout, bnacc);
  k1_gather<<<NREG, 256, 0, stream>>>(x, ln1_g, ln1_b, tok, aln);
  k2_qkv<<<dim3(NREG, 4), 256, 0, stream>>>(aln, wqkvT, qkvt);
  k3_attn<<<dim3(NREG, NHEADS), 256, 0, stream>>>(qkvt, o);
  k4_outproj<<<dim3(NREG, 4), 256, 0, stream>>>(o, awout, b_out, tok);
  k5_merge<<<dim3(HH_, BB), 512, 0, stream>>>(tok, ln2_g, ln2_b, xf, xln);
  k6_p0<<<dim3(256, BB), 256, 0, stream>>>(xln, ap0, b_p0, ym);
  k7_conv<<<BB * HID, 256, 0, stream>>>(ym, dw_k, ym2, bnacc);
  k8_fin<<<1, 256, 0, stream>>>(bnacc, bnm, bnr);
  k9_act<<<8192, 256, 0, stream>>>(ym2, bnm, bnr, bn_g, bn_b, g2b);
  k10_p2<<<dim3(256, BB), 256, 0, stream>>>(g2b, ap2, b_p2, xf, outp);
}